// Round 3
// baseline (1111.231 us; speedup 1.0000x reference)
//
#include <hip/hip_runtime.h>
#include <math.h>

// Problem constants (match reference)
#define NN     50000
#define EE     800000
#define ETOT   (EE + NN)      // edges + self loops = 850000
#define INDIM  128
#define HEADS  4
#define NG     128
#define NEGS   0.2f
#define BNEPS  1e-5f

// ---------------------------------------------------------------------------
// CSR build: degree histogram
__global__ void degree_kernel(const int* __restrict__ ei, int* __restrict__ deg) {
    int e = blockIdx.x * blockDim.x + threadIdx.x;
    if (e >= ETOT) return;
    int d = (e < EE) ? ei[EE + e] : (e - EE);
    atomicAdd(&deg[d], 1);
}

// Block-wise exclusive scan (1024/block), Hillis-Steele
__global__ void scan_block_kernel(const int* __restrict__ deg, int* __restrict__ rowstart,
                                  int* __restrict__ bsums) {
    __shared__ int tmp[1024];
    int tid = threadIdx.x;
    int i = blockIdx.x * 1024 + tid;
    int v = (i < NN) ? deg[i] : 0;
    tmp[tid] = v;
    __syncthreads();
    for (int off = 1; off < 1024; off <<= 1) {
        int t = (tid >= off) ? tmp[tid - off] : 0;
        __syncthreads();
        tmp[tid] += t;
        __syncthreads();
    }
    if (i < NN) rowstart[i] = tmp[tid] - v;   // exclusive
    if (tid == 1023) bsums[blockIdx.x] = tmp[tid];
}

__global__ void scan_sums_kernel(int* __restrict__ bsums, int nb) {
    if (threadIdx.x == 0 && blockIdx.x == 0) {
        int acc = 0;
        for (int i = 0; i < nb; ++i) { int t = bsums[i]; bsums[i] = acc; acc += t; }
    }
}

__global__ void add_offsets_kernel(int* __restrict__ rowstart, const int* __restrict__ bsums) {
    int i = blockIdx.x * blockDim.x + threadIdx.x;
    if (i < NN) rowstart[i] += bsums[i >> 10];
}

__global__ void scatter_kernel(const int* __restrict__ ei, const int* __restrict__ rowstart,
                               int* __restrict__ fill, int* __restrict__ csr_src,
                               int* __restrict__ csr_dst, int* __restrict__ csr_eid) {
    int e = blockIdx.x * blockDim.x + threadIdx.x;
    if (e >= ETOT) return;
    int s, d;
    if (e < EE) { s = ei[e]; d = ei[EE + e]; }
    else        { s = e - EE; d = e - EE; }
    int pos = rowstart[d] + atomicAdd(&fill[d], 1);
    csr_src[pos] = s;
    csr_dst[pos] = d;
    csr_eid[pos] = e;
}

// ---------------------------------------------------------------------------
// Fused GEMM (h = x @ W^T) + attention dot products per node.
// Block = 256 threads = 4 waves; block tile = 32 nodes; each wave owns 8 rows
// with acc[8] register blocking; col = lane.
// sW stride is 65 (not 64): staging writes walk k with fixed c, so stride-64
// put all 64 lanes on one bank (measured 2.48e7 SQ_LDS_BANK_CONFLICT); the
// +1 pad makes both the transposed writes and the stride-1 reads conflict-free.
template <int DD>
__global__ __launch_bounds__(256) void gemm_att_kernel(
    const float* __restrict__ X, const float* __restrict__ W,
    const float* __restrict__ attS, const float* __restrict__ attD,
    float* __restrict__ H, float* __restrict__ AS, float* __restrict__ AD) {
    __shared__ float sW[DD * 65];   // sW[k*65+c] = W[c*DD+k]
    __shared__ float sX[32][DD];
    int tid = threadIdx.x;
    // Stage W: float4 global loads, 4 padded-stride LDS writes each.
    for (int i = tid * 4; i < 64 * DD; i += 1024) {
        int c = i / DD, k = i % DD;
        float4 w = *(const float4*)(W + i);
        sW[(k + 0) * 65 + c] = w.x;
        sW[(k + 1) * 65 + c] = w.y;
        sW[(k + 2) * 65 + c] = w.z;
        sW[(k + 3) * 65 + c] = w.w;
    }
    int base = blockIdx.x * 32;
    float4* sX4 = (float4*)(&sX[0][0]);
    for (int i = tid; i < 32 * DD / 4; i += 256) {
        int node = base + i / (DD / 4);
        sX4[i] = (node < NN) ? ((const float4*)X)[(size_t)base * (DD / 4) + i]
                             : make_float4(0.f, 0.f, 0.f, 0.f);
    }
    __syncthreads();

    int col = tid & 63;
    int wv = tid >> 6;          // 0..3
    int r0 = wv * 8;
    int head = col >> 4;
    float acc[8] = {0.f, 0.f, 0.f, 0.f, 0.f, 0.f, 0.f, 0.f};
#pragma unroll
    for (int k = 0; k < DD; k += 4) {
        float w0 = sW[(k + 0) * 65 + col];
        float w1 = sW[(k + 1) * 65 + col];
        float w2 = sW[(k + 2) * 65 + col];
        float w3 = sW[(k + 3) * 65 + col];
#pragma unroll
        for (int r = 0; r < 8; ++r) {
            float4 xv = *(const float4*)&sX[r0 + r][k];
            acc[r] = fmaf(xv.x, w0, acc[r]);
            acc[r] = fmaf(xv.y, w1, acc[r]);
            acc[r] = fmaf(xv.z, w2, acc[r]);
            acc[r] = fmaf(xv.w, w3, acc[r]);
        }
    }
    float as_c = attS[col];
    float ad_c = attD[col];
#pragma unroll
    for (int r = 0; r < 8; ++r) {
        int node = base + r0 + r;     // wave-uniform
        if (node < NN) {
            H[(size_t)node * 64 + col] = acc[r];
            float vs = acc[r] * as_c;
            float vd = acc[r] * ad_c;
#pragma unroll
            for (int off = 8; off; off >>= 1) {
                vs += __shfl_down(vs, off, 16);
                vd += __shfl_down(vd, off, 16);
            }
            if ((col & 15) == 0) {
                AS[node * 4 + head] = vs;
                AD[node * 4 + head] = vd;
            }
        }
    }
}

// ---------------------------------------------------------------------------
// Edge-parallel: P[j][h] = exp(leaky_relu(AS[src[j]][h] + AD[dst[j]][h])).
// No max-subtraction: logits are O(1) here (normalized activations, att~0.1),
// exp cannot overflow; softmax value is mathematically identical.
__global__ __launch_bounds__(256) void edge_p_kernel(
    const int* __restrict__ csr_src, const int* __restrict__ csr_dst,
    const float* __restrict__ AS, const float* __restrict__ AD,
    float* __restrict__ P) {
    int j = blockIdx.x * blockDim.x + threadIdx.x;
    if (j >= ETOT) return;
    int s = csr_src[j], d = csr_dst[j];
    float4 as = *(const float4*)(AS + (size_t)s * 4);
    float4 ad = *(const float4*)(AD + (size_t)d * 4);
    float4 p;
    float l;
    l = as.x + ad.x; l = l > 0.f ? l : NEGS * l; p.x = __expf(l);
    l = as.y + ad.y; l = l > 0.f ? l : NEGS * l; p.y = __expf(l);
    l = as.z + ad.z; l = l > 0.f ? l : NEGS * l; p.z = __expf(l);
    l = as.w + ad.w; l = l > 0.f ? l : NEGS * l; p.w = __expf(l);
    *(float4*)(P + (size_t)j * 4) = p;
}

// ---------------------------------------------------------------------------
// Per-node aggregation: z = sum p, acc = sum p*H[src]; fused bias+ReLU+BN.
// One wave per node; lane = head*16 + channel. 1-deep prefetch of (s,p) to
// overlap the indirect H row load.
template <bool WRITE_Z>
__global__ __launch_bounds__(256) void edge_aggr_kernel(
    const float* __restrict__ H, const float* __restrict__ P,
    const int* __restrict__ rowstart, const int* __restrict__ deg,
    const int* __restrict__ csr_src,
    const float* __restrict__ bias, const float* __restrict__ gamma,
    const float* __restrict__ beta, const float* __restrict__ mean,
    const float* __restrict__ var, float* __restrict__ Hout,
    float* __restrict__ Z) {
    int v = (blockIdx.x * blockDim.x + threadIdx.x) >> 6;
    if (v >= NN) return;
    int lane = threadIdx.x & 63;
    int head = lane >> 4;
    int start = rowstart[v];
    int cnt = deg[v];                    // >= 1 (self loop)
    const float* prow = P + (size_t)start * 4 + head;
    const int* srow = csr_src + start;
    float z = 0.f, acc = 0.f;
    int s_n = srow[0];
    float p_n = prow[0];
    for (int k = 0; k < cnt; ++k) {
        int s = s_n;
        float p = p_n;
        if (k + 1 < cnt) {               // uniform branch
            s_n = srow[k + 1];
            p_n = prow[4 * (k + 1)];
        }
        float hv = H[(size_t)s * 64 + lane];
        z += p;
        acc = fmaf(p, hv, acc);
    }
    if (WRITE_Z && (lane & 15) == 0) Z[v * 4 + head] = z;
    float res = acc / z + bias[lane];
    res = fmaxf(res, 0.f);
    res = gamma[lane] * (res - mean[lane]) * rsqrtf(var[lane] + BNEPS) + beta[lane];
    Hout[(size_t)v * 64 + lane] = res;
}

// ---------------------------------------------------------------------------
// Layer-0 alpha write-back: alpha[eid][h] = P[j][h] / Z[dst[j]][h]
__global__ __launch_bounds__(256) void alpha_kernel(
    const float* __restrict__ P, const float* __restrict__ Z,
    const int* __restrict__ csr_dst, const int* __restrict__ csr_eid,
    float* __restrict__ alpha_out) {
    int j = blockIdx.x * blockDim.x + threadIdx.x;
    if (j >= ETOT) return;
    int d = csr_dst[j], e = csr_eid[j];
    float4 p = *(const float4*)(P + (size_t)j * 4);
    float4 z = *(const float4*)(Z + (size_t)d * 4);
    float4 a;
    a.x = p.x / z.x; a.y = p.y / z.y; a.z = p.z / z.z; a.w = p.w / z.w;
    *(float4*)(alpha_out + (size_t)e * 4) = a;
}

// ---------------------------------------------------------------------------
// Mean pool over sorted batch ids: one wave per 64-node chunk, local
// accumulation, atomic flush on graph-id change.
__global__ __launch_bounds__(256) void pool_kernel(const float* __restrict__ H,
                                                   const int* __restrict__ batch,
                                                   float* __restrict__ sums,
                                                   int* __restrict__ cnt) {
    int wid = (blockIdx.x * blockDim.x + threadIdx.x) >> 6;
    int lane = threadIdx.x & 63;
    int base = wid * 64;
    if (base >= NN) return;
    int end = min(base + 64, NN);
    int cur = batch[base];
    float acc = 0.f;
    int c0 = 0;
    for (int i = base; i < end; ++i) {
        int g = batch[i];
        if (g != cur) {
            atomicAdd(&sums[cur * 64 + lane], acc);
            if (lane == 0) atomicAdd(&cnt[cur], c0);
            cur = g; acc = 0.f; c0 = 0;
        }
        acc += H[(size_t)i * 64 + lane];
        c0++;
    }
    atomicAdd(&sums[cur * 64 + lane], acc);
    if (lane == 0) atomicAdd(&cnt[cur], c0);
}

__global__ void fc_kernel(const float* __restrict__ sums, const int* __restrict__ cnt,
                          const float* __restrict__ fcW, const float* __restrict__ fcb,
                          float* __restrict__ out) {
    int g = (blockIdx.x * blockDim.x + threadIdx.x) >> 6;
    int lane = threadIdx.x & 63;
    if (g >= NG) return;
    float c = fmaxf((float)cnt[g], 1.f);
    float val = (sums[g * 64 + lane] / c) * fcW[lane];
#pragma unroll
    for (int off = 32; off; off >>= 1) val += __shfl_down(val, off, 64);
    if (lane == 0) out[g] = 1.f / (1.f + expf(-(val + fcb[0])));
}

// ---------------------------------------------------------------------------
extern "C" void kernel_launch(void* const* d_in, const int* in_sizes, int n_in,
                              void* d_out, int out_size, void* d_ws, size_t ws_size,
                              hipStream_t stream) {
    const float* x   = (const float*)d_in[0];
    const int* ei    = (const int*)d_in[1];
    const int* batch = (const int*)d_in[2];
    const float* W[3], *attS[3], *attD[3], *bias[3], *gamma[3], *beta[3], *mean[3], *var[3];
    for (int l = 0; l < 3; ++l) {
        W[l]     = (const float*)d_in[3 + 8 * l + 0];
        attS[l]  = (const float*)d_in[3 + 8 * l + 1];
        attD[l]  = (const float*)d_in[3 + 8 * l + 2];
        bias[l]  = (const float*)d_in[3 + 8 * l + 3];
        gamma[l] = (const float*)d_in[3 + 8 * l + 4];
        beta[l]  = (const float*)d_in[3 + 8 * l + 5];
        mean[l]  = (const float*)d_in[3 + 8 * l + 6];
        var[l]   = (const float*)d_in[3 + 8 * l + 7];
    }
    const float* fcW = (const float*)d_in[27];
    const float* fcb = (const float*)d_in[28];
    float* out = (float*)d_out;               // [128] pooled sigmoid
    float* alpha_out = (float*)d_out + NG;    // [850000*4] layer-0 alpha

    // Workspace carve-up (256B aligned)
    char* p = (char*)d_ws;
    auto carve = [&](size_t bytes) {
        char* q = p;
        p += (bytes + 255) & ~(size_t)255;
        return q;
    };
    float* hA       = (float*)carve(sizeof(float) * NN * 64);
    float* hB       = (float*)carve(sizeof(float) * NN * 64);
    float* AS       = (float*)carve(sizeof(float) * NN * 4);
    float* AD       = (float*)carve(sizeof(float) * NN * 4);
    float* Z        = (float*)carve(sizeof(float) * NN * 4);
    float* P        = (float*)carve(sizeof(float) * ETOT * 4);
    int*   rowstart = (int*)carve(sizeof(int) * NN);
    int*   deg      = (int*)carve(sizeof(int) * NN);
    int*   fill     = (int*)carve(sizeof(int) * NN);
    int*   bsums    = (int*)carve(sizeof(int) * 64);
    int*   csr_src  = (int*)carve(sizeof(int) * ETOT);
    int*   csr_dst  = (int*)carve(sizeof(int) * ETOT);
    int*   csr_eid  = (int*)carve(sizeof(int) * ETOT);
    float* psums    = (float*)carve(sizeof(float) * NG * 64);
    int*   pcnt     = (int*)carve(sizeof(int) * NG);

    hipMemsetAsync(deg, 0, sizeof(int) * NN, stream);
    hipMemsetAsync(fill, 0, sizeof(int) * NN, stream);
    hipMemsetAsync(psums, 0, sizeof(float) * NG * 64, stream);
    hipMemsetAsync(pcnt, 0, sizeof(int) * NG, stream);

    // CSR build
    int nbScan = (NN + 1023) / 1024;
    degree_kernel<<<(ETOT + 255) / 256, 256, 0, stream>>>(ei, deg);
    scan_block_kernel<<<nbScan, 1024, 0, stream>>>(deg, rowstart, bsums);
    scan_sums_kernel<<<1, 64, 0, stream>>>(bsums, nbScan);
    add_offsets_kernel<<<(NN + 255) / 256, 256, 0, stream>>>(rowstart, bsums);
    scatter_kernel<<<(ETOT + 255) / 256, 256, 0, stream>>>(ei, rowstart, fill,
                                                           csr_src, csr_dst, csr_eid);

    int edgeBlocks = (NN * 64 + 255) / 256;
    int posBlocks = (ETOT + 255) / 256;
    int gemmBlocks = (NN + 31) / 32;   // 1563

    // Layer 0 (input dim 128), writes Z then alpha
    gemm_att_kernel<128><<<gemmBlocks, 256, 0, stream>>>(x, W[0], attS[0], attD[0], hA, AS, AD);
    edge_p_kernel<<<posBlocks, 256, 0, stream>>>(csr_src, csr_dst, AS, AD, P);
    edge_aggr_kernel<true><<<edgeBlocks, 256, 0, stream>>>(
        hA, P, rowstart, deg, csr_src,
        bias[0], gamma[0], beta[0], mean[0], var[0], hB, Z);
    alpha_kernel<<<posBlocks, 256, 0, stream>>>(P, Z, csr_dst, csr_eid, alpha_out);

    // Layer 1
    gemm_att_kernel<64><<<gemmBlocks, 256, 0, stream>>>(hB, W[1], attS[1], attD[1], hA, AS, AD);
    edge_p_kernel<<<posBlocks, 256, 0, stream>>>(csr_src, csr_dst, AS, AD, P);
    edge_aggr_kernel<false><<<edgeBlocks, 256, 0, stream>>>(
        hA, P, rowstart, deg, csr_src,
        bias[1], gamma[1], beta[1], mean[1], var[1], hB, nullptr);

    // Layer 2
    gemm_att_kernel<64><<<gemmBlocks, 256, 0, stream>>>(hB, W[2], attS[2], attD[2], hA, AS, AD);
    edge_p_kernel<<<posBlocks, 256, 0, stream>>>(csr_src, csr_dst, AS, AD, P);
    edge_aggr_kernel<false><<<edgeBlocks, 256, 0, stream>>>(
        hA, P, rowstart, deg, csr_src,
        bias[2], gamma[2], beta[2], mean[2], var[2], hB, nullptr);

    // Pool + FC
    int poolWaves = (NN + 63) / 64;
    pool_kernel<<<(poolWaves * 64 + 255) / 256, 256, 0, stream>>>(hB, batch, psums, pcnt);
    fc_kernel<<<(NG * 64 + 255) / 256, 256, 0, stream>>>(psums, pcnt, fcW, fcb, out);
}

// Round 4
// 549.124 us; speedup vs baseline: 2.0236x; 2.0236x over previous
//
#include <hip/hip_runtime.h>
#include <math.h>

// Problem constants (match reference)
#define NN     50000
#define EE     800000
#define ETOT   (EE + NN)      // edges + self loops = 850000
#define INDIM  128
#define HEADS  4
#define NG     128
#define NEGS   0.2f
#define BNEPS  1e-5f

// ---------------------------------------------------------------------------
// CSR build: degree histogram
__global__ void degree_kernel(const int* __restrict__ ei, int* __restrict__ deg) {
    int e = blockIdx.x * blockDim.x + threadIdx.x;
    if (e >= ETOT) return;
    int d = (e < EE) ? ei[EE + e] : (e - EE);
    atomicAdd(&deg[d], 1);
}

// Block-wise exclusive scan (1024/block), Hillis-Steele
__global__ void scan_block_kernel(const int* __restrict__ deg, int* __restrict__ rowstart,
                                  int* __restrict__ bsums) {
    __shared__ int tmp[1024];
    int tid = threadIdx.x;
    int i = blockIdx.x * 1024 + tid;
    int v = (i < NN) ? deg[i] : 0;
    tmp[tid] = v;
    __syncthreads();
    for (int off = 1; off < 1024; off <<= 1) {
        int t = (tid >= off) ? tmp[tid - off] : 0;
        __syncthreads();
        tmp[tid] += t;
        __syncthreads();
    }
    if (i < NN) rowstart[i] = tmp[tid] - v;   // exclusive
    if (tid == 1023) bsums[blockIdx.x] = tmp[tid];
}

__global__ void scan_sums_kernel(int* __restrict__ bsums, int nb) {
    if (threadIdx.x == 0 && blockIdx.x == 0) {
        int acc = 0;
        for (int i = 0; i < nb; ++i) { int t = bsums[i]; bsums[i] = acc; acc += t; }
    }
}

__global__ void add_offsets_kernel(int* __restrict__ rowstart, const int* __restrict__ bsums) {
    int i = blockIdx.x * blockDim.x + threadIdx.x;
    if (i < NN) rowstart[i] += bsums[i >> 10];
}

__global__ void scatter_kernel(const int* __restrict__ ei, const int* __restrict__ rowstart,
                               int* __restrict__ fill, int* __restrict__ csr_src,
                               int* __restrict__ csr_dst, int* __restrict__ csr_eid) {
    int e = blockIdx.x * blockDim.x + threadIdx.x;
    if (e >= ETOT) return;
    int s, d;
    if (e < EE) { s = ei[e]; d = ei[EE + e]; }
    else        { s = e - EE; d = e - EE; }
    int pos = rowstart[d] + atomicAdd(&fill[d], 1);
    csr_src[pos] = s;
    csr_dst[pos] = d;
    csr_eid[pos] = e;
}

// ---------------------------------------------------------------------------
// Fused GEMM (h = x @ W^T) + attention dot products per node.
// Block = 256 threads = 4 waves; block tile = 16 nodes; each wave owns 4 rows
// with acc[4] register blocking; col = lane. NN % 16 == 0 so no tail checks.
// sW stride 65 (not 64): transpose-staging writes walk k at fixed c; stride-64
// put all lanes on one bank (R2 measured 2.48e7 SQ_LDS_BANK_CONFLICT ~= 40us).
// R3 NOTE: acc[8]+full unroll spilled (VGPR 256, 1.5GB scratch traffic) —
// keep acc[4] + unroll 4 (VGPR 52, no spill).
template <int DD>
__global__ __launch_bounds__(256) void gemm_att_kernel(
    const float* __restrict__ X, const float* __restrict__ W,
    const float* __restrict__ attS, const float* __restrict__ attD,
    float* __restrict__ H, float* __restrict__ AS, float* __restrict__ AD) {
    __shared__ float sW[DD * 65];   // sW[k*65+c] = W[c*DD+k]
    __shared__ float sX[16][DD];
    int tid = threadIdx.x;
    // Stage W: float4 global loads, padded-stride LDS writes (conflict-free).
    for (int i = tid * 4; i < 64 * DD; i += 1024) {
        int c = i / DD, k = i % DD;
        float4 w = *(const float4*)(W + i);
        sW[(k + 0) * 65 + c] = w.x;
        sW[(k + 1) * 65 + c] = w.y;
        sW[(k + 2) * 65 + c] = w.z;
        sW[(k + 3) * 65 + c] = w.w;
    }
    int base = blockIdx.x * 16;
    const float4* X4 = (const float4*)(X + (size_t)base * DD);
    float4* sX4 = (float4*)(&sX[0][0]);
    for (int i = tid; i < 16 * DD / 4; i += 256) sX4[i] = X4[i];
    __syncthreads();

    int col = tid & 63;
    int wv = tid >> 6;          // 0..3
    int r0 = wv * 4;
    int head = col >> 4;
    float acc[4] = {0.f, 0.f, 0.f, 0.f};
#pragma unroll 4
    for (int k = 0; k < DD; k += 4) {
        float w0 = sW[(k + 0) * 65 + col];
        float w1 = sW[(k + 1) * 65 + col];
        float w2 = sW[(k + 2) * 65 + col];
        float w3 = sW[(k + 3) * 65 + col];
#pragma unroll
        for (int r = 0; r < 4; ++r) {
            float4 xv = *(const float4*)&sX[r0 + r][k];
            acc[r] = fmaf(xv.x, w0, acc[r]);
            acc[r] = fmaf(xv.y, w1, acc[r]);
            acc[r] = fmaf(xv.z, w2, acc[r]);
            acc[r] = fmaf(xv.w, w3, acc[r]);
        }
    }
    float as_c = attS[col];
    float ad_c = attD[col];
#pragma unroll
    for (int r = 0; r < 4; ++r) {
        int node = base + r0 + r;
        H[(size_t)node * 64 + col] = acc[r];
        float vs = acc[r] * as_c;
        float vd = acc[r] * ad_c;
#pragma unroll
        for (int off = 8; off; off >>= 1) {
            vs += __shfl_down(vs, off, 16);
            vd += __shfl_down(vd, off, 16);
        }
        if ((col & 15) == 0) {
            AS[node * 4 + head] = vs;
            AD[node * 4 + head] = vd;
        }
    }
}

// ---------------------------------------------------------------------------
// Edge-parallel: P[j][h] = exp(leaky_relu(AS[src[j]][h] + AD[dst[j]][h])).
// No max-subtraction: logits are O(1) here (normalized activations, att~0.1),
// exp cannot overflow; softmax value is mathematically identical.
__global__ __launch_bounds__(256) void edge_p_kernel(
    const int* __restrict__ csr_src, const int* __restrict__ csr_dst,
    const float* __restrict__ AS, const float* __restrict__ AD,
    float* __restrict__ P) {
    int j = blockIdx.x * blockDim.x + threadIdx.x;
    if (j >= ETOT) return;
    int s = csr_src[j], d = csr_dst[j];
    float4 as = *(const float4*)(AS + (size_t)s * 4);
    float4 ad = *(const float4*)(AD + (size_t)d * 4);
    float4 p;
    float l;
    l = as.x + ad.x; l = l > 0.f ? l : NEGS * l; p.x = __expf(l);
    l = as.y + ad.y; l = l > 0.f ? l : NEGS * l; p.y = __expf(l);
    l = as.z + ad.z; l = l > 0.f ? l : NEGS * l; p.z = __expf(l);
    l = as.w + ad.w; l = l > 0.f ? l : NEGS * l; p.w = __expf(l);
    *(float4*)(P + (size_t)j * 4) = p;
}

// ---------------------------------------------------------------------------
// Per-node aggregation: z = sum p, acc = sum p*H[src]; fused bias+ReLU+BN.
// One wave per node; lane = head*16 + channel. 1-deep prefetch of (s,p) to
// overlap the indirect H row load.
template <bool WRITE_Z>
__global__ __launch_bounds__(256) void edge_aggr_kernel(
    const float* __restrict__ H, const float* __restrict__ P,
    const int* __restrict__ rowstart, const int* __restrict__ deg,
    const int* __restrict__ csr_src,
    const float* __restrict__ bias, const float* __restrict__ gamma,
    const float* __restrict__ beta, const float* __restrict__ mean,
    const float* __restrict__ var, float* __restrict__ Hout,
    float* __restrict__ Z) {
    int v = (blockIdx.x * blockDim.x + threadIdx.x) >> 6;
    if (v >= NN) return;
    int lane = threadIdx.x & 63;
    int head = lane >> 4;
    int start = rowstart[v];
    int cnt = deg[v];                    // >= 1 (self loop)
    const float* prow = P + (size_t)start * 4 + head;
    const int* srow = csr_src + start;
    float z = 0.f, acc = 0.f;
    int s_n = srow[0];
    float p_n = prow[0];
    for (int k = 0; k < cnt; ++k) {
        int s = s_n;
        float p = p_n;
        if (k + 1 < cnt) {               // uniform branch
            s_n = srow[k + 1];
            p_n = prow[4 * (k + 1)];
        }
        float hv = H[(size_t)s * 64 + lane];
        z += p;
        acc = fmaf(p, hv, acc);
    }
    if (WRITE_Z && (lane & 15) == 0) Z[v * 4 + head] = z;
    float res = acc / z + bias[lane];
    res = fmaxf(res, 0.f);
    res = gamma[lane] * (res - mean[lane]) * rsqrtf(var[lane] + BNEPS) + beta[lane];
    Hout[(size_t)v * 64 + lane] = res;
}

// ---------------------------------------------------------------------------
// Layer-0 alpha write-back: alpha[eid][h] = P[j][h] / Z[dst[j]][h]
__global__ __launch_bounds__(256) void alpha_kernel(
    const float* __restrict__ P, const float* __restrict__ Z,
    const int* __restrict__ csr_dst, const int* __restrict__ csr_eid,
    float* __restrict__ alpha_out) {
    int j = blockIdx.x * blockDim.x + threadIdx.x;
    if (j >= ETOT) return;
    int d = csr_dst[j], e = csr_eid[j];
    float4 p = *(const float4*)(P + (size_t)j * 4);
    float4 z = *(const float4*)(Z + (size_t)d * 4);
    float4 a;
    a.x = p.x / z.x; a.y = p.y / z.y; a.z = p.z / z.z; a.w = p.w / z.w;
    *(float4*)(alpha_out + (size_t)e * 4) = a;
}

// ---------------------------------------------------------------------------
// Mean pool over sorted batch ids: one wave per 64-node chunk, local
// accumulation, atomic flush on graph-id change.
__global__ __launch_bounds__(256) void pool_kernel(const float* __restrict__ H,
                                                   const int* __restrict__ batch,
                                                   float* __restrict__ sums,
                                                   int* __restrict__ cnt) {
    int wid = (blockIdx.x * blockDim.x + threadIdx.x) >> 6;
    int lane = threadIdx.x & 63;
    int base = wid * 64;
    if (base >= NN) return;
    int end = min(base + 64, NN);
    int cur = batch[base];
    float acc = 0.f;
    int c0 = 0;
    for (int i = base; i < end; ++i) {
        int g = batch[i];
        if (g != cur) {
            atomicAdd(&sums[cur * 64 + lane], acc);
            if (lane == 0) atomicAdd(&cnt[cur], c0);
            cur = g; acc = 0.f; c0 = 0;
        }
        acc += H[(size_t)i * 64 + lane];
        c0++;
    }
    atomicAdd(&sums[cur * 64 + lane], acc);
    if (lane == 0) atomicAdd(&cnt[cur], c0);
}

__global__ void fc_kernel(const float* __restrict__ sums, const int* __restrict__ cnt,
                          const float* __restrict__ fcW, const float* __restrict__ fcb,
                          float* __restrict__ out) {
    int g = (blockIdx.x * blockDim.x + threadIdx.x) >> 6;
    int lane = threadIdx.x & 63;
    if (g >= NG) return;
    float c = fmaxf((float)cnt[g], 1.f);
    float val = (sums[g * 64 + lane] / c) * fcW[lane];
#pragma unroll
    for (int off = 32; off; off >>= 1) val += __shfl_down(val, off, 64);
    if (lane == 0) out[g] = 1.f / (1.f + expf(-(val + fcb[0])));
}

// ---------------------------------------------------------------------------
extern "C" void kernel_launch(void* const* d_in, const int* in_sizes, int n_in,
                              void* d_out, int out_size, void* d_ws, size_t ws_size,
                              hipStream_t stream) {
    const float* x   = (const float*)d_in[0];
    const int* ei    = (const int*)d_in[1];
    const int* batch = (const int*)d_in[2];
    const float* W[3], *attS[3], *attD[3], *bias[3], *gamma[3], *beta[3], *mean[3], *var[3];
    for (int l = 0; l < 3; ++l) {
        W[l]     = (const float*)d_in[3 + 8 * l + 0];
        attS[l]  = (const float*)d_in[3 + 8 * l + 1];
        attD[l]  = (const float*)d_in[3 + 8 * l + 2];
        bias[l]  = (const float*)d_in[3 + 8 * l + 3];
        gamma[l] = (const float*)d_in[3 + 8 * l + 4];
        beta[l]  = (const float*)d_in[3 + 8 * l + 5];
        mean[l]  = (const float*)d_in[3 + 8 * l + 6];
        var[l]   = (const float*)d_in[3 + 8 * l + 7];
    }
    const float* fcW = (const float*)d_in[27];
    const float* fcb = (const float*)d_in[28];
    float* out = (float*)d_out;               // [128] pooled sigmoid
    float* alpha_out = (float*)d_out + NG;    // [850000*4] layer-0 alpha

    // Workspace carve-up (256B aligned)
    char* p = (char*)d_ws;
    auto carve = [&](size_t bytes) {
        char* q = p;
        p += (bytes + 255) & ~(size_t)255;
        return q;
    };
    float* hA       = (float*)carve(sizeof(float) * NN * 64);
    float* hB       = (float*)carve(sizeof(float) * NN * 64);
    float* AS       = (float*)carve(sizeof(float) * NN * 4);
    float* AD       = (float*)carve(sizeof(float) * NN * 4);
    float* Z        = (float*)carve(sizeof(float) * NN * 4);
    float* P        = (float*)carve(sizeof(float) * ETOT * 4);
    int*   rowstart = (int*)carve(sizeof(int) * NN);
    int*   deg      = (int*)carve(sizeof(int) * NN);
    int*   fill     = (int*)carve(sizeof(int) * NN);
    int*   bsums    = (int*)carve(sizeof(int) * 64);
    int*   csr_src  = (int*)carve(sizeof(int) * ETOT);
    int*   csr_dst  = (int*)carve(sizeof(int) * ETOT);
    int*   csr_eid  = (int*)carve(sizeof(int) * ETOT);
    float* psums    = (float*)carve(sizeof(float) * NG * 64);
    int*   pcnt     = (int*)carve(sizeof(int) * NG);

    hipMemsetAsync(deg, 0, sizeof(int) * NN, stream);
    hipMemsetAsync(fill, 0, sizeof(int) * NN, stream);
    hipMemsetAsync(psums, 0, sizeof(float) * NG * 64, stream);
    hipMemsetAsync(pcnt, 0, sizeof(int) * NG, stream);

    // CSR build
    int nbScan = (NN + 1023) / 1024;
    degree_kernel<<<(ETOT + 255) / 256, 256, 0, stream>>>(ei, deg);
    scan_block_kernel<<<nbScan, 1024, 0, stream>>>(deg, rowstart, bsums);
    scan_sums_kernel<<<1, 64, 0, stream>>>(bsums, nbScan);
    add_offsets_kernel<<<(NN + 255) / 256, 256, 0, stream>>>(rowstart, bsums);
    scatter_kernel<<<(ETOT + 255) / 256, 256, 0, stream>>>(ei, rowstart, fill,
                                                           csr_src, csr_dst, csr_eid);

    int edgeBlocks = (NN * 64 + 255) / 256;
    int posBlocks = (ETOT + 255) / 256;
    int gemmBlocks = NN / 16;   // 3125, exact

    // Layer 0 (input dim 128), writes Z then alpha
    gemm_att_kernel<128><<<gemmBlocks, 256, 0, stream>>>(x, W[0], attS[0], attD[0], hA, AS, AD);
    edge_p_kernel<<<posBlocks, 256, 0, stream>>>(csr_src, csr_dst, AS, AD, P);
    edge_aggr_kernel<true><<<edgeBlocks, 256, 0, stream>>>(
        hA, P, rowstart, deg, csr_src,
        bias[0], gamma[0], beta[0], mean[0], var[0], hB, Z);
    alpha_kernel<<<posBlocks, 256, 0, stream>>>(P, Z, csr_dst, csr_eid, alpha_out);

    // Layer 1
    gemm_att_kernel<64><<<gemmBlocks, 256, 0, stream>>>(hB, W[1], attS[1], attD[1], hA, AS, AD);
    edge_p_kernel<<<posBlocks, 256, 0, stream>>>(csr_src, csr_dst, AS, AD, P);
    edge_aggr_kernel<false><<<edgeBlocks, 256, 0, stream>>>(
        hA, P, rowstart, deg, csr_src,
        bias[1], gamma[1], beta[1], mean[1], var[1], hB, nullptr);

    // Layer 2
    gemm_att_kernel<64><<<gemmBlocks, 256, 0, stream>>>(hB, W[2], attS[2], attD[2], hA, AS, AD);
    edge_p_kernel<<<posBlocks, 256, 0, stream>>>(csr_src, csr_dst, AS, AD, P);
    edge_aggr_kernel<false><<<edgeBlocks, 256, 0, stream>>>(
        hA, P, rowstart, deg, csr_src,
        bias[2], gamma[2], beta[2], mean[2], var[2], hB, nullptr);

    // Pool + FC
    int poolWaves = (NN + 63) / 64;
    pool_kernel<<<(poolWaves * 64 + 255) / 256, 256, 0, stream>>>(hB, batch, psums, pcnt);
    fc_kernel<<<(NG * 64 + 255) / 256, 256, 0, stream>>>(psums, pcnt, fcW, fcb, out);
}

// Round 5
// 487.212 us; speedup vs baseline: 2.2808x; 1.1271x over previous
//
#include <hip/hip_runtime.h>
#include <math.h>

// Problem constants (match reference)
#define NN     50000
#define EE     800000
#define ETOT   (EE + NN)      // edges + self loops = 850000
#define INDIM  128
#define HEADS  4
#define NG     128
#define NEGS   0.2f
#define BNEPS  1e-5f

// ---------------------------------------------------------------------------
// CSR build: degree histogram
__global__ void degree_kernel(const int* __restrict__ ei, int* __restrict__ deg) {
    int e = blockIdx.x * blockDim.x + threadIdx.x;
    if (e >= ETOT) return;
    int d = (e < EE) ? ei[EE + e] : (e - EE);
    atomicAdd(&deg[d], 1);
}

// Block-wise exclusive scan (1024/block), Hillis-Steele
__global__ void scan_block_kernel(const int* __restrict__ deg, int* __restrict__ rowstart,
                                  int* __restrict__ bsums) {
    __shared__ int tmp[1024];
    int tid = threadIdx.x;
    int i = blockIdx.x * 1024 + tid;
    int v = (i < NN) ? deg[i] : 0;
    tmp[tid] = v;
    __syncthreads();
    for (int off = 1; off < 1024; off <<= 1) {
        int t = (tid >= off) ? tmp[tid - off] : 0;
        __syncthreads();
        tmp[tid] += t;
        __syncthreads();
    }
    if (i < NN) rowstart[i] = tmp[tid] - v;   // exclusive
    if (tid == 1023) bsums[blockIdx.x] = tmp[tid];
}

__global__ void scan_sums_kernel(int* __restrict__ bsums, int nb) {
    if (threadIdx.x == 0 && blockIdx.x == 0) {
        int acc = 0;
        for (int i = 0; i < nb; ++i) { int t = bsums[i]; bsums[i] = acc; acc += t; }
    }
}

__global__ void add_offsets_kernel(int* __restrict__ rowstart, const int* __restrict__ bsums) {
    int i = blockIdx.x * blockDim.x + threadIdx.x;
    if (i < NN) rowstart[i] += bsums[i >> 10];
}

__global__ void scatter_kernel(const int* __restrict__ ei, const int* __restrict__ rowstart,
                               int* __restrict__ fill, int* __restrict__ csr_src,
                               int* __restrict__ csr_dst, int* __restrict__ csr_eid) {
    int e = blockIdx.x * blockDim.x + threadIdx.x;
    if (e >= ETOT) return;
    int s, d;
    if (e < EE) { s = ei[e]; d = ei[EE + e]; }
    else        { s = e - EE; d = e - EE; }
    int pos = rowstart[d] + atomicAdd(&fill[d], 1);
    csr_src[pos] = s;
    csr_dst[pos] = d;
    csr_eid[pos] = e;
}

// ---------------------------------------------------------------------------
// Fused GEMM (h = x @ W^T) + attention dot products per node.
// Block = 256 threads = 4 waves; block tile = 16 nodes; each wave owns 4 rows
// with acc[4] register blocking; col = lane. NN % 16 == 0 so no tail checks.
// sW stride 65 (not 64): transpose-staging writes walk k at fixed c; stride-64
// put all lanes on one bank (R2 measured 2.48e7 SQ_LDS_BANK_CONFLICT ~= 40us).
// R3 NOTE: acc[8]+full unroll spilled (VGPR 256, 1.5GB scratch traffic) —
// keep acc[4] + unroll 4 (VGPR 52, no spill).
template <int DD>
__global__ __launch_bounds__(256) void gemm_att_kernel(
    const float* __restrict__ X, const float* __restrict__ W,
    const float* __restrict__ attS, const float* __restrict__ attD,
    float* __restrict__ H, float* __restrict__ AS, float* __restrict__ AD) {
    __shared__ float sW[DD * 65];   // sW[k*65+c] = W[c*DD+k]
    __shared__ float sX[16][DD];
    int tid = threadIdx.x;
    // Stage W: float4 global loads, padded-stride LDS writes (conflict-free).
    for (int i = tid * 4; i < 64 * DD; i += 1024) {
        int c = i / DD, k = i % DD;
        float4 w = *(const float4*)(W + i);
        sW[(k + 0) * 65 + c] = w.x;
        sW[(k + 1) * 65 + c] = w.y;
        sW[(k + 2) * 65 + c] = w.z;
        sW[(k + 3) * 65 + c] = w.w;
    }
    int base = blockIdx.x * 16;
    const float4* X4 = (const float4*)(X + (size_t)base * DD);
    float4* sX4 = (float4*)(&sX[0][0]);
    for (int i = tid; i < 16 * DD / 4; i += 256) sX4[i] = X4[i];
    __syncthreads();

    int col = tid & 63;
    int wv = tid >> 6;          // 0..3
    int r0 = wv * 4;
    int head = col >> 4;
    float acc[4] = {0.f, 0.f, 0.f, 0.f};
#pragma unroll 4
    for (int k = 0; k < DD; k += 4) {
        float w0 = sW[(k + 0) * 65 + col];
        float w1 = sW[(k + 1) * 65 + col];
        float w2 = sW[(k + 2) * 65 + col];
        float w3 = sW[(k + 3) * 65 + col];
#pragma unroll
        for (int r = 0; r < 4; ++r) {
            float4 xv = *(const float4*)&sX[r0 + r][k];
            acc[r] = fmaf(xv.x, w0, acc[r]);
            acc[r] = fmaf(xv.y, w1, acc[r]);
            acc[r] = fmaf(xv.z, w2, acc[r]);
            acc[r] = fmaf(xv.w, w3, acc[r]);
        }
    }
    float as_c = attS[col];
    float ad_c = attD[col];
#pragma unroll
    for (int r = 0; r < 4; ++r) {
        int node = base + r0 + r;
        H[(size_t)node * 64 + col] = acc[r];
        float vs = acc[r] * as_c;
        float vd = acc[r] * ad_c;
#pragma unroll
        for (int off = 8; off; off >>= 1) {
            vs += __shfl_down(vs, off, 16);
            vd += __shfl_down(vd, off, 16);
        }
        if ((col & 15) == 0) {
            AS[node * 4 + head] = vs;
            AD[node * 4 + head] = vd;
        }
    }
}

// ---------------------------------------------------------------------------
// Edge-parallel: P[j][h] = exp(leaky_relu(AS[src[j]][h] + AD[dst[j]][h])).
// No max-subtraction: logits are O(1) here (normalized activations, att~0.1),
// exp cannot overflow; softmax value is mathematically identical.
__global__ __launch_bounds__(256) void edge_p_kernel(
    const int* __restrict__ csr_src, const int* __restrict__ csr_dst,
    const float* __restrict__ AS, const float* __restrict__ AD,
    float* __restrict__ P) {
    int j = blockIdx.x * blockDim.x + threadIdx.x;
    if (j >= ETOT) return;
    int s = csr_src[j], d = csr_dst[j];
    float4 as = *(const float4*)(AS + (size_t)s * 4);
    float4 ad = *(const float4*)(AD + (size_t)d * 4);
    float4 p;
    float l;
    l = as.x + ad.x; l = l > 0.f ? l : NEGS * l; p.x = __expf(l);
    l = as.y + ad.y; l = l > 0.f ? l : NEGS * l; p.y = __expf(l);
    l = as.z + ad.z; l = l > 0.f ? l : NEGS * l; p.z = __expf(l);
    l = as.w + ad.w; l = l > 0.f ? l : NEGS * l; p.w = __expf(l);
    *(float4*)(P + (size_t)j * 4) = p;
}

// ---------------------------------------------------------------------------
// Per-node aggregation: z = sum p, acc = sum p*H[src]; fused bias+ReLU+BN.
// One wave per node; lane = head*16 + channel.
// R4: loop was latency-bound (VALUBusy 30%, HBM 21%, 1 dependent gather per
// iter). Unroll x4: load 4 (s,p) pairs then issue 4 INDEPENDENT H-row gathers
// before the FMAs — 4x memory-level parallelism per wave.
template <bool WRITE_Z>
__global__ __launch_bounds__(256) void edge_aggr_kernel(
    const float* __restrict__ H, const float* __restrict__ P,
    const int* __restrict__ rowstart, const int* __restrict__ deg,
    const int* __restrict__ csr_src,
    const float* __restrict__ bias, const float* __restrict__ gamma,
    const float* __restrict__ beta, const float* __restrict__ mean,
    const float* __restrict__ var, float* __restrict__ Hout,
    float* __restrict__ Z) {
    int v = (blockIdx.x * blockDim.x + threadIdx.x) >> 6;
    if (v >= NN) return;
    int lane = threadIdx.x & 63;
    int head = lane >> 4;
    int start = rowstart[v];
    int cnt = deg[v];                    // >= 1 (self loop)
    const float* prow = P + (size_t)start * 4 + head;
    const int* srow = csr_src + start;
    float z = 0.f, acc = 0.f;
    int k = 0;
    for (; k + 4 <= cnt; k += 4) {
        int s0 = srow[k + 0];
        int s1 = srow[k + 1];
        int s2 = srow[k + 2];
        int s3 = srow[k + 3];
        float p0 = prow[4 * (k + 0)];
        float p1 = prow[4 * (k + 1)];
        float p2 = prow[4 * (k + 2)];
        float p3 = prow[4 * (k + 3)];
        float h0 = H[(size_t)s0 * 64 + lane];
        float h1 = H[(size_t)s1 * 64 + lane];
        float h2 = H[(size_t)s2 * 64 + lane];
        float h3 = H[(size_t)s3 * 64 + lane];
        z += (p0 + p1) + (p2 + p3);
        acc = fmaf(p0, h0, acc);
        acc = fmaf(p1, h1, acc);
        acc = fmaf(p2, h2, acc);
        acc = fmaf(p3, h3, acc);
    }
    for (; k < cnt; ++k) {
        int s = srow[k];
        float p = prow[4 * k];
        float hv = H[(size_t)s * 64 + lane];
        z += p;
        acc = fmaf(p, hv, acc);
    }
    if (WRITE_Z && (lane & 15) == 0) Z[v * 4 + head] = z;
    float res = acc / z + bias[lane];
    res = fmaxf(res, 0.f);
    res = gamma[lane] * (res - mean[lane]) * rsqrtf(var[lane] + BNEPS) + beta[lane];
    Hout[(size_t)v * 64 + lane] = res;
}

// ---------------------------------------------------------------------------
// Layer-0 alpha write-back: alpha[eid][h] = P[j][h] / Z[dst[j]][h]
__global__ __launch_bounds__(256) void alpha_kernel(
    const float* __restrict__ P, const float* __restrict__ Z,
    const int* __restrict__ csr_dst, const int* __restrict__ csr_eid,
    float* __restrict__ alpha_out) {
    int j = blockIdx.x * blockDim.x + threadIdx.x;
    if (j >= ETOT) return;
    int d = csr_dst[j], e = csr_eid[j];
    float4 p = *(const float4*)(P + (size_t)j * 4);
    float4 z = *(const float4*)(Z + (size_t)d * 4);
    float4 a;
    a.x = p.x / z.x; a.y = p.y / z.y; a.z = p.z / z.z; a.w = p.w / z.w;
    *(float4*)(alpha_out + (size_t)e * 4) = a;
}

// ---------------------------------------------------------------------------
// Mean pool over sorted batch ids: one wave per 64-node chunk, local
// accumulation, atomic flush on graph-id change.
__global__ __launch_bounds__(256) void pool_kernel(const float* __restrict__ H,
                                                   const int* __restrict__ batch,
                                                   float* __restrict__ sums,
                                                   int* __restrict__ cnt) {
    int wid = (blockIdx.x * blockDim.x + threadIdx.x) >> 6;
    int lane = threadIdx.x & 63;
    int base = wid * 64;
    if (base >= NN) return;
    int end = min(base + 64, NN);
    int cur = batch[base];
    float acc = 0.f;
    int c0 = 0;
    for (int i = base; i < end; ++i) {
        int g = batch[i];
        if (g != cur) {
            atomicAdd(&sums[cur * 64 + lane], acc);
            if (lane == 0) atomicAdd(&cnt[cur], c0);
            cur = g; acc = 0.f; c0 = 0;
        }
        acc += H[(size_t)i * 64 + lane];
        c0++;
    }
    atomicAdd(&sums[cur * 64 + lane], acc);
    if (lane == 0) atomicAdd(&cnt[cur], c0);
}

__global__ void fc_kernel(const float* __restrict__ sums, const int* __restrict__ cnt,
                          const float* __restrict__ fcW, const float* __restrict__ fcb,
                          float* __restrict__ out) {
    int g = (blockIdx.x * blockDim.x + threadIdx.x) >> 6;
    int lane = threadIdx.x & 63;
    if (g >= NG) return;
    float c = fmaxf((float)cnt[g], 1.f);
    float val = (sums[g * 64 + lane] / c) * fcW[lane];
#pragma unroll
    for (int off = 32; off; off >>= 1) val += __shfl_down(val, off, 64);
    if (lane == 0) out[g] = 1.f / (1.f + expf(-(val + fcb[0])));
}

// ---------------------------------------------------------------------------
extern "C" void kernel_launch(void* const* d_in, const int* in_sizes, int n_in,
                              void* d_out, int out_size, void* d_ws, size_t ws_size,
                              hipStream_t stream) {
    const float* x   = (const float*)d_in[0];
    const int* ei    = (const int*)d_in[1];
    const int* batch = (const int*)d_in[2];
    const float* W[3], *attS[3], *attD[3], *bias[3], *gamma[3], *beta[3], *mean[3], *var[3];
    for (int l = 0; l < 3; ++l) {
        W[l]     = (const float*)d_in[3 + 8 * l + 0];
        attS[l]  = (const float*)d_in[3 + 8 * l + 1];
        attD[l]  = (const float*)d_in[3 + 8 * l + 2];
        bias[l]  = (const float*)d_in[3 + 8 * l + 3];
        gamma[l] = (const float*)d_in[3 + 8 * l + 4];
        beta[l]  = (const float*)d_in[3 + 8 * l + 5];
        mean[l]  = (const float*)d_in[3 + 8 * l + 6];
        var[l]   = (const float*)d_in[3 + 8 * l + 7];
    }
    const float* fcW = (const float*)d_in[27];
    const float* fcb = (const float*)d_in[28];
    float* out = (float*)d_out;               // [128] pooled sigmoid
    float* alpha_out = (float*)d_out + NG;    // [850000*4] layer-0 alpha

    // Workspace carve-up (256B aligned)
    char* p = (char*)d_ws;
    auto carve = [&](size_t bytes) {
        char* q = p;
        p += (bytes + 255) & ~(size_t)255;
        return q;
    };
    float* hA       = (float*)carve(sizeof(float) * NN * 64);
    float* hB       = (float*)carve(sizeof(float) * NN * 64);
    float* AS       = (float*)carve(sizeof(float) * NN * 4);
    float* AD       = (float*)carve(sizeof(float) * NN * 4);
    float* Z        = (float*)carve(sizeof(float) * NN * 4);
    float* P        = (float*)carve(sizeof(float) * ETOT * 4);
    int*   rowstart = (int*)carve(sizeof(int) * NN);
    int*   deg      = (int*)carve(sizeof(int) * NN);
    int*   fill     = (int*)carve(sizeof(int) * NN);
    int*   bsums    = (int*)carve(sizeof(int) * 64);
    int*   csr_src  = (int*)carve(sizeof(int) * ETOT);
    int*   csr_dst  = (int*)carve(sizeof(int) * ETOT);
    int*   csr_eid  = (int*)carve(sizeof(int) * ETOT);
    float* psums    = (float*)carve(sizeof(float) * NG * 64);
    int*   pcnt     = (int*)carve(sizeof(int) * NG);

    hipMemsetAsync(deg, 0, sizeof(int) * NN, stream);
    hipMemsetAsync(fill, 0, sizeof(int) * NN, stream);
    hipMemsetAsync(psums, 0, sizeof(float) * NG * 64, stream);
    hipMemsetAsync(pcnt, 0, sizeof(int) * NG, stream);

    // CSR build
    int nbScan = (NN + 1023) / 1024;
    degree_kernel<<<(ETOT + 255) / 256, 256, 0, stream>>>(ei, deg);
    scan_block_kernel<<<nbScan, 1024, 0, stream>>>(deg, rowstart, bsums);
    scan_sums_kernel<<<1, 64, 0, stream>>>(bsums, nbScan);
    add_offsets_kernel<<<(NN + 255) / 256, 256, 0, stream>>>(rowstart, bsums);
    scatter_kernel<<<(ETOT + 255) / 256, 256, 0, stream>>>(ei, rowstart, fill,
                                                           csr_src, csr_dst, csr_eid);

    int edgeBlocks = (NN * 64 + 255) / 256;
    int posBlocks = (ETOT + 255) / 256;
    int gemmBlocks = NN / 16;   // 3125, exact

    // Layer 0 (input dim 128), writes Z then alpha
    gemm_att_kernel<128><<<gemmBlocks, 256, 0, stream>>>(x, W[0], attS[0], attD[0], hA, AS, AD);
    edge_p_kernel<<<posBlocks, 256, 0, stream>>>(csr_src, csr_dst, AS, AD, P);
    edge_aggr_kernel<true><<<edgeBlocks, 256, 0, stream>>>(
        hA, P, rowstart, deg, csr_src,
        bias[0], gamma[0], beta[0], mean[0], var[0], hB, Z);
    alpha_kernel<<<posBlocks, 256, 0, stream>>>(P, Z, csr_dst, csr_eid, alpha_out);

    // Layer 1
    gemm_att_kernel<64><<<gemmBlocks, 256, 0, stream>>>(hB, W[1], attS[1], attD[1], hA, AS, AD);
    edge_p_kernel<<<posBlocks, 256, 0, stream>>>(csr_src, csr_dst, AS, AD, P);
    edge_aggr_kernel<false><<<edgeBlocks, 256, 0, stream>>>(
        hA, P, rowstart, deg, csr_src,
        bias[1], gamma[1], beta[1], mean[1], var[1], hB, nullptr);

    // Layer 2
    gemm_att_kernel<64><<<gemmBlocks, 256, 0, stream>>>(hB, W[2], attS[2], attD[2], hA, AS, AD);
    edge_p_kernel<<<posBlocks, 256, 0, stream>>>(csr_src, csr_dst, AS, AD, P);
    edge_aggr_kernel<false><<<edgeBlocks, 256, 0, stream>>>(
        hA, P, rowstart, deg, csr_src,
        bias[2], gamma[2], beta[2], mean[2], var[2], hB, nullptr);

    // Pool + FC
    int poolWaves = (NN + 63) / 64;
    pool_kernel<<<(poolWaves * 64 + 255) / 256, 256, 0, stream>>>(hB, batch, psums, pcnt);
    fc_kernel<<<(NG * 64 + 255) / 256, 256, 0, stream>>>(psums, pcnt, fcW, fcb, out);
}

// Round 6
// 484.757 us; speedup vs baseline: 2.2923x; 1.0051x over previous
//
#include <hip/hip_runtime.h>
#include <math.h>

// Problem constants (match reference)
#define NN     50000
#define EE     800000
#define ETOT   (EE + NN)      // edges + self loops = 850000
#define INDIM  128
#define HEADS  4
#define NG     128
#define NEGS   0.2f
#define BNEPS  1e-5f

// CSR entry: packed (src, dst, eid, pad) so the random-position scatter is a
// SINGLE 16B store instead of three 4B stores to three arrays (R5: 3 partial
// sector writes/edge -> WRITE_SIZE 109MB, scatter 55us write-bound).

// ---------------------------------------------------------------------------
// CSR build: degree histogram
__global__ void degree_kernel(const int* __restrict__ ei, int* __restrict__ deg) {
    int e = blockIdx.x * blockDim.x + threadIdx.x;
    if (e >= ETOT) return;
    int d = (e < EE) ? ei[EE + e] : (e - EE);
    atomicAdd(&deg[d], 1);
}

// Block-wise exclusive scan (1024/block), Hillis-Steele
__global__ void scan_block_kernel(const int* __restrict__ deg, int* __restrict__ rowstart,
                                  int* __restrict__ bsums) {
    __shared__ int tmp[1024];
    int tid = threadIdx.x;
    int i = blockIdx.x * 1024 + tid;
    int v = (i < NN) ? deg[i] : 0;
    tmp[tid] = v;
    __syncthreads();
    for (int off = 1; off < 1024; off <<= 1) {
        int t = (tid >= off) ? tmp[tid - off] : 0;
        __syncthreads();
        tmp[tid] += t;
        __syncthreads();
    }
    if (i < NN) rowstart[i] = tmp[tid] - v;   // exclusive
    if (tid == 1023) bsums[blockIdx.x] = tmp[tid];
}

__global__ void scan_sums_kernel(int* __restrict__ bsums, int nb) {
    if (threadIdx.x == 0 && blockIdx.x == 0) {
        int acc = 0;
        for (int i = 0; i < nb; ++i) { int t = bsums[i]; bsums[i] = acc; acc += t; }
    }
}

__global__ void add_offsets_kernel(int* __restrict__ rowstart, const int* __restrict__ bsums) {
    int i = blockIdx.x * blockDim.x + threadIdx.x;
    if (i < NN) rowstart[i] += bsums[i >> 10];
}

__global__ void scatter_kernel(const int* __restrict__ ei, const int* __restrict__ rowstart,
                               int* __restrict__ fill, int4* __restrict__ csr) {
    int e = blockIdx.x * blockDim.x + threadIdx.x;
    if (e >= ETOT) return;
    int s, d;
    if (e < EE) { s = ei[e]; d = ei[EE + e]; }
    else        { s = e - EE; d = e - EE; }
    int pos = rowstart[d] + atomicAdd(&fill[d], 1);
    csr[pos] = make_int4(s, d, e, 0);
}

// ---------------------------------------------------------------------------
// Fused GEMM (h = x @ W^T) + attention dot products per node.
// Block = 256 threads = 4 waves; block tile = 16 nodes; each wave owns 4 rows
// with acc[4] register blocking; col = lane. NN % 16 == 0 so no tail checks.
// sW stride 65 (not 64): transpose-staging writes walk k at fixed c; stride-64
// put all lanes on one bank (R2 measured 2.48e7 SQ_LDS_BANK_CONFLICT ~= 40us).
// R3 NOTE: acc[8]+full unroll spilled (VGPR 256, 1.5GB scratch traffic) —
// keep acc[4] + unroll 4 (VGPR 52, no spill).
template <int DD>
__global__ __launch_bounds__(256) void gemm_att_kernel(
    const float* __restrict__ X, const float* __restrict__ W,
    const float* __restrict__ attS, const float* __restrict__ attD,
    float* __restrict__ H, float* __restrict__ AS, float* __restrict__ AD) {
    __shared__ float sW[DD * 65];   // sW[k*65+c] = W[c*DD+k]
    __shared__ float sX[16][DD];
    int tid = threadIdx.x;
    // Stage W: float4 global loads, padded-stride LDS writes (conflict-free).
    for (int i = tid * 4; i < 64 * DD; i += 1024) {
        int c = i / DD, k = i % DD;
        float4 w = *(const float4*)(W + i);
        sW[(k + 0) * 65 + c] = w.x;
        sW[(k + 1) * 65 + c] = w.y;
        sW[(k + 2) * 65 + c] = w.z;
        sW[(k + 3) * 65 + c] = w.w;
    }
    int base = blockIdx.x * 16;
    const float4* X4 = (const float4*)(X + (size_t)base * DD);
    float4* sX4 = (float4*)(&sX[0][0]);
    for (int i = tid; i < 16 * DD / 4; i += 256) sX4[i] = X4[i];
    __syncthreads();

    int col = tid & 63;
    int wv = tid >> 6;          // 0..3
    int r0 = wv * 4;
    int head = col >> 4;
    float acc[4] = {0.f, 0.f, 0.f, 0.f};
#pragma unroll 4
    for (int k = 0; k < DD; k += 4) {
        float w0 = sW[(k + 0) * 65 + col];
        float w1 = sW[(k + 1) * 65 + col];
        float w2 = sW[(k + 2) * 65 + col];
        float w3 = sW[(k + 3) * 65 + col];
#pragma unroll
        for (int r = 0; r < 4; ++r) {
            float4 xv = *(const float4*)&sX[r0 + r][k];
            acc[r] = fmaf(xv.x, w0, acc[r]);
            acc[r] = fmaf(xv.y, w1, acc[r]);
            acc[r] = fmaf(xv.z, w2, acc[r]);
            acc[r] = fmaf(xv.w, w3, acc[r]);
        }
    }
    float as_c = attS[col];
    float ad_c = attD[col];
#pragma unroll
    for (int r = 0; r < 4; ++r) {
        int node = base + r0 + r;
        H[(size_t)node * 64 + col] = acc[r];
        float vs = acc[r] * as_c;
        float vd = acc[r] * ad_c;
#pragma unroll
        for (int off = 8; off; off >>= 1) {
            vs += __shfl_down(vs, off, 16);
            vd += __shfl_down(vd, off, 16);
        }
        if ((col & 15) == 0) {
            AS[node * 4 + head] = vs;
            AD[node * 4 + head] = vd;
        }
    }
}

// ---------------------------------------------------------------------------
// Edge-parallel: P[j][h] = exp(leaky_relu(AS[src[j]][h] + AD[dst[j]][h])).
// No max-subtraction: logits are O(1) here (normalized activations, att~0.1),
// exp cannot overflow; softmax value is mathematically identical.
__global__ __launch_bounds__(256) void edge_p_kernel(
    const int4* __restrict__ csr,
    const float* __restrict__ AS, const float* __restrict__ AD,
    float* __restrict__ P) {
    int j = blockIdx.x * blockDim.x + threadIdx.x;
    if (j >= ETOT) return;
    int4 en = csr[j];
    float4 as = *(const float4*)(AS + (size_t)en.x * 4);
    float4 ad = *(const float4*)(AD + (size_t)en.y * 4);
    float4 p;
    float l;
    l = as.x + ad.x; l = l > 0.f ? l : NEGS * l; p.x = __expf(l);
    l = as.y + ad.y; l = l > 0.f ? l : NEGS * l; p.y = __expf(l);
    l = as.z + ad.z; l = l > 0.f ? l : NEGS * l; p.z = __expf(l);
    l = as.w + ad.w; l = l > 0.f ? l : NEGS * l; p.w = __expf(l);
    *(float4*)(P + (size_t)j * 4) = p;
}

// ---------------------------------------------------------------------------
// Per-node aggregation: z = sum p, acc = sum p*H[src]; fused bias+ReLU+BN.
// One wave per node; lane = head*16 + channel.
// R4: loop was latency-bound (VALUBusy 30%, HBM 21%, 1 dependent gather per
// iter). Unroll x4: load 4 (s,p) pairs then issue 4 INDEPENDENT H-row gathers
// before the FMAs — 4x memory-level parallelism per wave.
template <bool WRITE_Z>
__global__ __launch_bounds__(256) void edge_aggr_kernel(
    const float* __restrict__ H, const float* __restrict__ P,
    const int* __restrict__ rowstart, const int* __restrict__ deg,
    const int4* __restrict__ csr,
    const float* __restrict__ bias, const float* __restrict__ gamma,
    const float* __restrict__ beta, const float* __restrict__ mean,
    const float* __restrict__ var, float* __restrict__ Hout,
    float* __restrict__ Z) {
    int v = (blockIdx.x * blockDim.x + threadIdx.x) >> 6;
    if (v >= NN) return;
    int lane = threadIdx.x & 63;
    int head = lane >> 4;
    int start = rowstart[v];
    int cnt = deg[v];                    // >= 1 (self loop)
    const float* prow = P + (size_t)start * 4 + head;
    const int4* srow = csr + start;
    float z = 0.f, acc = 0.f;
    int k = 0;
    for (; k + 4 <= cnt; k += 4) {
        int s0 = srow[k + 0].x;
        int s1 = srow[k + 1].x;
        int s2 = srow[k + 2].x;
        int s3 = srow[k + 3].x;
        float p0 = prow[4 * (k + 0)];
        float p1 = prow[4 * (k + 1)];
        float p2 = prow[4 * (k + 2)];
        float p3 = prow[4 * (k + 3)];
        float h0 = H[(size_t)s0 * 64 + lane];
        float h1 = H[(size_t)s1 * 64 + lane];
        float h2 = H[(size_t)s2 * 64 + lane];
        float h3 = H[(size_t)s3 * 64 + lane];
        z += (p0 + p1) + (p2 + p3);
        acc = fmaf(p0, h0, acc);
        acc = fmaf(p1, h1, acc);
        acc = fmaf(p2, h2, acc);
        acc = fmaf(p3, h3, acc);
    }
    for (; k < cnt; ++k) {
        int s = srow[k].x;
        float p = prow[4 * k];
        float hv = H[(size_t)s * 64 + lane];
        z += p;
        acc = fmaf(p, hv, acc);
    }
    if (WRITE_Z && (lane & 15) == 0) Z[v * 4 + head] = z;
    float res = acc / z + bias[lane];
    res = fmaxf(res, 0.f);
    res = gamma[lane] * (res - mean[lane]) * rsqrtf(var[lane] + BNEPS) + beta[lane];
    Hout[(size_t)v * 64 + lane] = res;
}

// ---------------------------------------------------------------------------
// Layer-0 alpha write-back: alpha[eid][h] = P[j][h] / Z[dst[j]][h]
__global__ __launch_bounds__(256) void alpha_kernel(
    const float* __restrict__ P, const float* __restrict__ Z,
    const int4* __restrict__ csr,
    float* __restrict__ alpha_out) {
    int j = blockIdx.x * blockDim.x + threadIdx.x;
    if (j >= ETOT) return;
    int4 en = csr[j];
    float4 p = *(const float4*)(P + (size_t)j * 4);
    float4 z = *(const float4*)(Z + (size_t)en.y * 4);
    float4 a;
    a.x = p.x / z.x; a.y = p.y / z.y; a.z = p.z / z.z; a.w = p.w / z.w;
    *(float4*)(alpha_out + (size_t)en.z * 4) = a;
}

// ---------------------------------------------------------------------------
// Mean pool over sorted batch ids: one wave per 64-node chunk, local
// accumulation, atomic flush on graph-id change.
__global__ __launch_bounds__(256) void pool_kernel(const float* __restrict__ H,
                                                   const int* __restrict__ batch,
                                                   float* __restrict__ sums,
                                                   int* __restrict__ cnt) {
    int wid = (blockIdx.x * blockDim.x + threadIdx.x) >> 6;
    int lane = threadIdx.x & 63;
    int base = wid * 64;
    if (base >= NN) return;
    int end = min(base + 64, NN);
    int cur = batch[base];
    float acc = 0.f;
    int c0 = 0;
    for (int i = base; i < end; ++i) {
        int g = batch[i];
        if (g != cur) {
            atomicAdd(&sums[cur * 64 + lane], acc);
            if (lane == 0) atomicAdd(&cnt[cur], c0);
            cur = g; acc = 0.f; c0 = 0;
        }
        acc += H[(size_t)i * 64 + lane];
        c0++;
    }
    atomicAdd(&sums[cur * 64 + lane], acc);
    if (lane == 0) atomicAdd(&cnt[cur], c0);
}

__global__ void fc_kernel(const float* __restrict__ sums, const int* __restrict__ cnt,
                          const float* __restrict__ fcW, const float* __restrict__ fcb,
                          float* __restrict__ out) {
    int g = (blockIdx.x * blockDim.x + threadIdx.x) >> 6;
    int lane = threadIdx.x & 63;
    if (g >= NG) return;
    float c = fmaxf((float)cnt[g], 1.f);
    float val = (sums[g * 64 + lane] / c) * fcW[lane];
#pragma unroll
    for (int off = 32; off; off >>= 1) val += __shfl_down(val, off, 64);
    if (lane == 0) out[g] = 1.f / (1.f + expf(-(val + fcb[0])));
}

// ---------------------------------------------------------------------------
extern "C" void kernel_launch(void* const* d_in, const int* in_sizes, int n_in,
                              void* d_out, int out_size, void* d_ws, size_t ws_size,
                              hipStream_t stream) {
    const float* x   = (const float*)d_in[0];
    const int* ei    = (const int*)d_in[1];
    const int* batch = (const int*)d_in[2];
    const float* W[3], *attS[3], *attD[3], *bias[3], *gamma[3], *beta[3], *mean[3], *var[3];
    for (int l = 0; l < 3; ++l) {
        W[l]     = (const float*)d_in[3 + 8 * l + 0];
        attS[l]  = (const float*)d_in[3 + 8 * l + 1];
        attD[l]  = (const float*)d_in[3 + 8 * l + 2];
        bias[l]  = (const float*)d_in[3 + 8 * l + 3];
        gamma[l] = (const float*)d_in[3 + 8 * l + 4];
        beta[l]  = (const float*)d_in[3 + 8 * l + 5];
        mean[l]  = (const float*)d_in[3 + 8 * l + 6];
        var[l]   = (const float*)d_in[3 + 8 * l + 7];
    }
    const float* fcW = (const float*)d_in[27];
    const float* fcb = (const float*)d_in[28];
    float* out = (float*)d_out;               // [128] pooled sigmoid
    float* alpha_out = (float*)d_out + NG;    // [850000*4] layer-0 alpha

    // Workspace carve-up (256B aligned)
    char* p = (char*)d_ws;
    auto carve = [&](size_t bytes) {
        char* q = p;
        p += (bytes + 255) & ~(size_t)255;
        return q;
    };
    float* hA       = (float*)carve(sizeof(float) * NN * 64);
    float* hB       = (float*)carve(sizeof(float) * NN * 64);
    float* AS       = (float*)carve(sizeof(float) * NN * 4);
    float* AD       = (float*)carve(sizeof(float) * NN * 4);
    float* Z        = (float*)carve(sizeof(float) * NN * 4);
    float* P        = (float*)carve(sizeof(float) * ETOT * 4);
    int*   rowstart = (int*)carve(sizeof(int) * NN);
    int*   deg      = (int*)carve(sizeof(int) * NN);
    int*   fill     = (int*)carve(sizeof(int) * NN);
    int*   bsums    = (int*)carve(sizeof(int) * 64);
    int4*  csr      = (int4*)carve(sizeof(int4) * ETOT);
    float* psums    = (float*)carve(sizeof(float) * NG * 64);
    int*   pcnt     = (int*)carve(sizeof(int) * NG);

    hipMemsetAsync(deg, 0, sizeof(int) * NN, stream);
    hipMemsetAsync(fill, 0, sizeof(int) * NN, stream);
    hipMemsetAsync(psums, 0, sizeof(float) * NG * 64, stream);
    hipMemsetAsync(pcnt, 0, sizeof(int) * NG, stream);

    // CSR build
    int nbScan = (NN + 1023) / 1024;
    degree_kernel<<<(ETOT + 255) / 256, 256, 0, stream>>>(ei, deg);
    scan_block_kernel<<<nbScan, 1024, 0, stream>>>(deg, rowstart, bsums);
    scan_sums_kernel<<<1, 64, 0, stream>>>(bsums, nbScan);
    add_offsets_kernel<<<(NN + 255) / 256, 256, 0, stream>>>(rowstart, bsums);
    scatter_kernel<<<(ETOT + 255) / 256, 256, 0, stream>>>(ei, rowstart, fill, csr);

    int edgeBlocks = (NN * 64 + 255) / 256;
    int posBlocks = (ETOT + 255) / 256;
    int gemmBlocks = NN / 16;   // 3125, exact

    // Layer 0 (input dim 128), writes Z then alpha
    gemm_att_kernel<128><<<gemmBlocks, 256, 0, stream>>>(x, W[0], attS[0], attD[0], hA, AS, AD);
    edge_p_kernel<<<posBlocks, 256, 0, stream>>>(csr, AS, AD, P);
    edge_aggr_kernel<true><<<edgeBlocks, 256, 0, stream>>>(
        hA, P, rowstart, deg, csr,
        bias[0], gamma[0], beta[0], mean[0], var[0], hB, Z);
    alpha_kernel<<<posBlocks, 256, 0, stream>>>(P, Z, csr, alpha_out);

    // Layer 1
    gemm_att_kernel<64><<<gemmBlocks, 256, 0, stream>>>(hB, W[1], attS[1], attD[1], hA, AS, AD);
    edge_p_kernel<<<posBlocks, 256, 0, stream>>>(csr, AS, AD, P);
    edge_aggr_kernel<false><<<edgeBlocks, 256, 0, stream>>>(
        hA, P, rowstart, deg, csr,
        bias[1], gamma[1], beta[1], mean[1], var[1], hB, nullptr);

    // Layer 2
    gemm_att_kernel<64><<<gemmBlocks, 256, 0, stream>>>(hB, W[2], attS[2], attD[2], hA, AS, AD);
    edge_p_kernel<<<posBlocks, 256, 0, stream>>>(csr, AS, AD, P);
    edge_aggr_kernel<false><<<edgeBlocks, 256, 0, stream>>>(
        hA, P, rowstart, deg, csr,
        bias[2], gamma[2], beta[2], mean[2], var[2], hB, nullptr);

    // Pool + FC
    int poolWaves = (NN + 63) / 64;
    pool_kernel<<<(poolWaves * 64 + 255) / 256, 256, 0, stream>>>(hB, batch, psums, pcnt);
    fc_kernel<<<(NG * 64 + 255) / 256, 256, 0, stream>>>(psums, pcnt, fcW, fcb, out);
}

// Round 7
// 432.868 us; speedup vs baseline: 2.5671x; 1.1199x over previous
//
#include <hip/hip_runtime.h>
#include <math.h>

// Problem constants (match reference)
#define NN     50000
#define EE     800000
#define ETOT   (EE + NN)      // edges + self loops = 850000
#define INDIM  128
#define HEADS  4
#define NG     128
#define NEGS   0.2f
#define BNEPS  1e-5f

// ---------------------------------------------------------------------------
// CSR build. R6 post-mortem: scatter was latency-bound on the dependent
// atomicAdd(fill)->store chain (VALUBusy 0.7%, 1.1 TB/s, 50us). Fix: capture
// the within-dst rank in degree_kernel (it already pays the random atomic),
// making scatter atomic-free: pos = rowstart[d] + rank[e].
__global__ void degree_kernel(const int* __restrict__ ei, int* __restrict__ deg,
                              int* __restrict__ rank) {
    int e = blockIdx.x * blockDim.x + threadIdx.x;
    if (e >= ETOT) return;
    int d = (e < EE) ? ei[EE + e] : (e - EE);
    rank[e] = atomicAdd(&deg[d], 1);
}

// Block-wise exclusive scan (1024/block), Hillis-Steele
__global__ void scan_block_kernel(const int* __restrict__ deg, int* __restrict__ rowstart,
                                  int* __restrict__ bsums) {
    __shared__ int tmp[1024];
    int tid = threadIdx.x;
    int i = blockIdx.x * 1024 + tid;
    int v = (i < NN) ? deg[i] : 0;
    tmp[tid] = v;
    __syncthreads();
    for (int off = 1; off < 1024; off <<= 1) {
        int t = (tid >= off) ? tmp[tid - off] : 0;
        __syncthreads();
        tmp[tid] += t;
        __syncthreads();
    }
    if (i < NN) rowstart[i] = tmp[tid] - v;   // exclusive
    if (tid == 1023) bsums[blockIdx.x] = tmp[tid];
}

__global__ void scan_sums_kernel(int* __restrict__ bsums, int nb) {
    if (threadIdx.x == 0 && blockIdx.x == 0) {
        int acc = 0;
        for (int i = 0; i < nb; ++i) { int t = bsums[i]; bsums[i] = acc; acc += t; }
    }
}

__global__ void add_offsets_kernel(int* __restrict__ rowstart, const int* __restrict__ bsums) {
    int i = blockIdx.x * blockDim.x + threadIdx.x;
    if (i < NN) rowstart[i] += bsums[i >> 10];
}

// Atomic-free scatter: packed int4 entry = single 16B store (R5: 3x4B stores
// cost 109MB WRITE_SIZE; packing halved it).
__global__ void scatter_kernel(const int* __restrict__ ei, const int* __restrict__ rowstart,
                               const int* __restrict__ rank, int4* __restrict__ csr) {
    int e = blockIdx.x * blockDim.x + threadIdx.x;
    if (e >= ETOT) return;
    int s, d;
    if (e < EE) { s = ei[e]; d = ei[EE + e]; }
    else        { s = e - EE; d = e - EE; }
    int pos = rowstart[d] + rank[e];
    csr[pos] = make_int4(s, d, e, 0);
}

// ---------------------------------------------------------------------------
// Fused GEMM (h = x @ W^T) + attention dot products per node.
// Block = 256 threads = 4 waves; block tile = 16 nodes; each wave owns 4 rows
// with acc[4] register blocking; col = lane. NN % 16 == 0 so no tail checks.
// sW stride 65 (not 64): transpose-staging writes walk k at fixed c; stride-64
// put all lanes on one bank (R2 measured 2.48e7 SQ_LDS_BANK_CONFLICT ~= 40us).
// R3 NOTE: acc[8]+full unroll spilled (VGPR 256, 1.5GB scratch traffic) —
// keep acc[4] + unroll 4 (VGPR 52, no spill).
template <int DD>
__global__ __launch_bounds__(256) void gemm_att_kernel(
    const float* __restrict__ X, const float* __restrict__ W,
    const float* __restrict__ attS, const float* __restrict__ attD,
    float* __restrict__ H, float* __restrict__ AS, float* __restrict__ AD) {
    __shared__ float sW[DD * 65];   // sW[k*65+c] = W[c*DD+k]
    __shared__ float sX[16][DD];
    int tid = threadIdx.x;
    // Stage W: float4 global loads, padded-stride LDS writes (conflict-free).
    for (int i = tid * 4; i < 64 * DD; i += 1024) {
        int c = i / DD, k = i % DD;
        float4 w = *(const float4*)(W + i);
        sW[(k + 0) * 65 + c] = w.x;
        sW[(k + 1) * 65 + c] = w.y;
        sW[(k + 2) * 65 + c] = w.z;
        sW[(k + 3) * 65 + c] = w.w;
    }
    int base = blockIdx.x * 16;
    const float4* X4 = (const float4*)(X + (size_t)base * DD);
    float4* sX4 = (float4*)(&sX[0][0]);
    for (int i = tid; i < 16 * DD / 4; i += 256) sX4[i] = X4[i];
    __syncthreads();

    int col = tid & 63;
    int wv = tid >> 6;          // 0..3
    int r0 = wv * 4;
    int head = col >> 4;
    float acc[4] = {0.f, 0.f, 0.f, 0.f};
#pragma unroll 4
    for (int k = 0; k < DD; k += 4) {
        float w0 = sW[(k + 0) * 65 + col];
        float w1 = sW[(k + 1) * 65 + col];
        float w2 = sW[(k + 2) * 65 + col];
        float w3 = sW[(k + 3) * 65 + col];
#pragma unroll
        for (int r = 0; r < 4; ++r) {
            float4 xv = *(const float4*)&sX[r0 + r][k];
            acc[r] = fmaf(xv.x, w0, acc[r]);
            acc[r] = fmaf(xv.y, w1, acc[r]);
            acc[r] = fmaf(xv.z, w2, acc[r]);
            acc[r] = fmaf(xv.w, w3, acc[r]);
        }
    }
    float as_c = attS[col];
    float ad_c = attD[col];
#pragma unroll
    for (int r = 0; r < 4; ++r) {
        int node = base + r0 + r;
        H[(size_t)node * 64 + col] = acc[r];
        float vs = acc[r] * as_c;
        float vd = acc[r] * ad_c;
#pragma unroll
        for (int off = 8; off; off >>= 1) {
            vs += __shfl_down(vs, off, 16);
            vd += __shfl_down(vd, off, 16);
        }
        if ((col & 15) == 0) {
            AS[node * 4 + head] = vs;
            AD[node * 4 + head] = vd;
        }
    }
}

// ---------------------------------------------------------------------------
// Per-node aggregation with INLINE attention weights (R7: edge_p kernel and
// the P array eliminated — p = exp(leaky(AS[s]+AD[v])) computed in-loop; the
// AS gather is one broadcast dword per 16-lane head group, independent of the
// H-row gather so the 4x unrolled MLP is preserved).
// No max-subtraction: logits are O(1) (normalized inputs, att~0.1) — exp
// cannot overflow; softmax identical.
// One wave per node; lane = head*16 + channel. Fused bias+ReLU+BN epilogue.
template <bool WRITE_Z>
__global__ __launch_bounds__(256) void edge_aggr_kernel(
    const float* __restrict__ H, const float* __restrict__ AS,
    const float* __restrict__ AD,
    const int* __restrict__ rowstart, const int* __restrict__ deg,
    const int4* __restrict__ csr,
    const float* __restrict__ bias, const float* __restrict__ gamma,
    const float* __restrict__ beta, const float* __restrict__ mean,
    const float* __restrict__ var, float* __restrict__ Hout,
    float* __restrict__ Z) {
    int v = (blockIdx.x * blockDim.x + threadIdx.x) >> 6;
    if (v >= NN) return;
    int lane = threadIdx.x & 63;
    int head = lane >> 4;
    float adv = AD[v * 4 + head];
    int start = rowstart[v];
    int cnt = deg[v];                    // >= 1 (self loop)
    const int4* srow = csr + start;
    float z = 0.f, acc = 0.f;
    int k = 0;
    for (; k + 4 <= cnt; k += 4) {
        int s0 = srow[k + 0].x;
        int s1 = srow[k + 1].x;
        int s2 = srow[k + 2].x;
        int s3 = srow[k + 3].x;
        float a0 = AS[(size_t)s0 * 4 + head];
        float a1 = AS[(size_t)s1 * 4 + head];
        float a2 = AS[(size_t)s2 * 4 + head];
        float a3 = AS[(size_t)s3 * 4 + head];
        float h0 = H[(size_t)s0 * 64 + lane];
        float h1 = H[(size_t)s1 * 64 + lane];
        float h2 = H[(size_t)s2 * 64 + lane];
        float h3 = H[(size_t)s3 * 64 + lane];
        float l0 = a0 + adv; l0 = l0 > 0.f ? l0 : NEGS * l0; float p0 = __expf(l0);
        float l1 = a1 + adv; l1 = l1 > 0.f ? l1 : NEGS * l1; float p1 = __expf(l1);
        float l2 = a2 + adv; l2 = l2 > 0.f ? l2 : NEGS * l2; float p2 = __expf(l2);
        float l3 = a3 + adv; l3 = l3 > 0.f ? l3 : NEGS * l3; float p3 = __expf(l3);
        z += (p0 + p1) + (p2 + p3);
        acc = fmaf(p0, h0, acc);
        acc = fmaf(p1, h1, acc);
        acc = fmaf(p2, h2, acc);
        acc = fmaf(p3, h3, acc);
    }
    for (; k < cnt; ++k) {
        int s = srow[k].x;
        float a = AS[(size_t)s * 4 + head];
        float hv = H[(size_t)s * 64 + lane];
        float l = a + adv; l = l > 0.f ? l : NEGS * l;
        float p = __expf(l);
        z += p;
        acc = fmaf(p, hv, acc);
    }
    if (WRITE_Z && (lane & 15) == 0) Z[v * 4 + head] = z;
    float res = acc / z + bias[lane];
    res = fmaxf(res, 0.f);
    res = gamma[lane] * (res - mean[lane]) * rsqrtf(var[lane] + BNEPS) + beta[lane];
    Hout[(size_t)v * 64 + lane] = res;
}

// ---------------------------------------------------------------------------
// Layer-0 alpha write-back: recompute p from AS/AD (identical formula+inputs
// as aggr => identical values), divide by Z, scatter to eid.
__global__ __launch_bounds__(256) void alpha_kernel(
    const float* __restrict__ AS, const float* __restrict__ AD,
    const float* __restrict__ Z, const int4* __restrict__ csr,
    float* __restrict__ alpha_out) {
    int j = blockIdx.x * blockDim.x + threadIdx.x;
    if (j >= ETOT) return;
    int4 en = csr[j];
    float4 as = *(const float4*)(AS + (size_t)en.x * 4);
    float4 ad = *(const float4*)(AD + (size_t)en.y * 4);
    float4 z4 = *(const float4*)(Z + (size_t)en.y * 4);
    float l;
    float4 a;
    l = as.x + ad.x; l = l > 0.f ? l : NEGS * l; a.x = __expf(l) / z4.x;
    l = as.y + ad.y; l = l > 0.f ? l : NEGS * l; a.y = __expf(l) / z4.y;
    l = as.z + ad.z; l = l > 0.f ? l : NEGS * l; a.z = __expf(l) / z4.z;
    l = as.w + ad.w; l = l > 0.f ? l : NEGS * l; a.w = __expf(l) / z4.w;
    *(float4*)(alpha_out + (size_t)en.z * 4) = a;
}

// ---------------------------------------------------------------------------
// Mean pool over sorted batch ids: one wave per 64-node chunk, local
// accumulation, atomic flush on graph-id change.
__global__ __launch_bounds__(256) void pool_kernel(const float* __restrict__ H,
                                                   const int* __restrict__ batch,
                                                   float* __restrict__ sums,
                                                   int* __restrict__ cnt) {
    int wid = (blockIdx.x * blockDim.x + threadIdx.x) >> 6;
    int lane = threadIdx.x & 63;
    int base = wid * 64;
    if (base >= NN) return;
    int end = min(base + 64, NN);
    int cur = batch[base];
    float acc = 0.f;
    int c0 = 0;
    for (int i = base; i < end; ++i) {
        int g = batch[i];
        if (g != cur) {
            atomicAdd(&sums[cur * 64 + lane], acc);
            if (lane == 0) atomicAdd(&cnt[cur], c0);
            cur = g; acc = 0.f; c0 = 0;
        }
        acc += H[(size_t)i * 64 + lane];
        c0++;
    }
    atomicAdd(&sums[cur * 64 + lane], acc);
    if (lane == 0) atomicAdd(&cnt[cur], c0);
}

__global__ void fc_kernel(const float* __restrict__ sums, const int* __restrict__ cnt,
                          const float* __restrict__ fcW, const float* __restrict__ fcb,
                          float* __restrict__ out) {
    int g = (blockIdx.x * blockDim.x + threadIdx.x) >> 6;
    int lane = threadIdx.x & 63;
    if (g >= NG) return;
    float c = fmaxf((float)cnt[g], 1.f);
    float val = (sums[g * 64 + lane] / c) * fcW[lane];
#pragma unroll
    for (int off = 32; off; off >>= 1) val += __shfl_down(val, off, 64);
    if (lane == 0) out[g] = 1.f / (1.f + expf(-(val + fcb[0])));
}

// ---------------------------------------------------------------------------
extern "C" void kernel_launch(void* const* d_in, const int* in_sizes, int n_in,
                              void* d_out, int out_size, void* d_ws, size_t ws_size,
                              hipStream_t stream) {
    const float* x   = (const float*)d_in[0];
    const int* ei    = (const int*)d_in[1];
    const int* batch = (const int*)d_in[2];
    const float* W[3], *attS[3], *attD[3], *bias[3], *gamma[3], *beta[3], *mean[3], *var[3];
    for (int l = 0; l < 3; ++l) {
        W[l]     = (const float*)d_in[3 + 8 * l + 0];
        attS[l]  = (const float*)d_in[3 + 8 * l + 1];
        attD[l]  = (const float*)d_in[3 + 8 * l + 2];
        bias[l]  = (const float*)d_in[3 + 8 * l + 3];
        gamma[l] = (const float*)d_in[3 + 8 * l + 4];
        beta[l]  = (const float*)d_in[3 + 8 * l + 5];
        mean[l]  = (const float*)d_in[3 + 8 * l + 6];
        var[l]   = (const float*)d_in[3 + 8 * l + 7];
    }
    const float* fcW = (const float*)d_in[27];
    const float* fcb = (const float*)d_in[28];
    float* out = (float*)d_out;               // [128] pooled sigmoid
    float* alpha_out = (float*)d_out + NG;    // [850000*4] layer-0 alpha

    // Workspace carve-up (256B aligned)
    char* p = (char*)d_ws;
    auto carve = [&](size_t bytes) {
        char* q = p;
        p += (bytes + 255) & ~(size_t)255;
        return q;
    };
    float* hA       = (float*)carve(sizeof(float) * NN * 64);
    float* hB       = (float*)carve(sizeof(float) * NN * 64);
    float* AS       = (float*)carve(sizeof(float) * NN * 4);
    float* AD       = (float*)carve(sizeof(float) * NN * 4);
    float* Z        = (float*)carve(sizeof(float) * NN * 4);
    int*   rowstart = (int*)carve(sizeof(int) * NN);
    int*   deg      = (int*)carve(sizeof(int) * NN);
    int*   rank     = (int*)carve(sizeof(int) * ETOT);
    int*   bsums    = (int*)carve(sizeof(int) * 64);
    int4*  csr      = (int4*)carve(sizeof(int4) * ETOT);
    float* psums    = (float*)carve(sizeof(float) * NG * 64);
    int*   pcnt     = (int*)carve(sizeof(int) * NG);

    hipMemsetAsync(deg, 0, sizeof(int) * NN, stream);
    hipMemsetAsync(psums, 0, sizeof(float) * NG * 64, stream);
    hipMemsetAsync(pcnt, 0, sizeof(int) * NG, stream);

    // CSR build
    int nbScan = (NN + 1023) / 1024;
    degree_kernel<<<(ETOT + 255) / 256, 256, 0, stream>>>(ei, deg, rank);
    scan_block_kernel<<<nbScan, 1024, 0, stream>>>(deg, rowstart, bsums);
    scan_sums_kernel<<<1, 64, 0, stream>>>(bsums, nbScan);
    add_offsets_kernel<<<(NN + 255) / 256, 256, 0, stream>>>(rowstart, bsums);
    scatter_kernel<<<(ETOT + 255) / 256, 256, 0, stream>>>(ei, rowstart, rank, csr);

    int edgeBlocks = (NN * 64 + 255) / 256;
    int posBlocks = (ETOT + 255) / 256;
    int gemmBlocks = NN / 16;   // 3125, exact

    // Layer 0 (input dim 128), writes Z then alpha
    gemm_att_kernel<128><<<gemmBlocks, 256, 0, stream>>>(x, W[0], attS[0], attD[0], hA, AS, AD);
    edge_aggr_kernel<true><<<edgeBlocks, 256, 0, stream>>>(
        hA, AS, AD, rowstart, deg, csr,
        bias[0], gamma[0], beta[0], mean[0], var[0], hB, Z);
    alpha_kernel<<<posBlocks, 256, 0, stream>>>(AS, AD, Z, csr, alpha_out);

    // Layer 1
    gemm_att_kernel<64><<<gemmBlocks, 256, 0, stream>>>(hB, W[1], attS[1], attD[1], hA, AS, AD);
    edge_aggr_kernel<false><<<edgeBlocks, 256, 0, stream>>>(
        hA, AS, AD, rowstart, deg, csr,
        bias[1], gamma[1], beta[1], mean[1], var[1], hB, nullptr);

    // Layer 2
    gemm_att_kernel<64><<<gemmBlocks, 256, 0, stream>>>(hB, W[2], attS[2], attD[2], hA, AS, AD);
    edge_aggr_kernel<false><<<edgeBlocks, 256, 0, stream>>>(
        hA, AS, AD, rowstart, deg, csr,
        bias[2], gamma[2], beta[2], mean[2], var[2], hB, nullptr);

    // Pool + FC
    int poolWaves = (NN + 63) / 64;
    pool_kernel<<<(poolWaves * 64 + 255) / 256, 256, 0, stream>>>(hB, batch, psums, pcnt);
    fc_kernel<<<(NG * 64 + 255) / 256, 256, 0, stream>>>(psums, pcnt, fcW, fcb, out);
}

// Round 8
// 425.534 us; speedup vs baseline: 2.6114x; 1.0172x over previous
//
#include <hip/hip_runtime.h>
#include <hip/hip_fp16.h>
#include <math.h>

// Problem constants (match reference)
#define NN     50000
#define EE     800000
#define ETOT   (EE + NN)      // edges + self loops = 850000
#define INDIM  128
#define HEADS  4
#define NG     128
#define NEGS   0.2f
#define BNEPS  1e-5f

// R8: gathered feature array hA stored as fp16 (half the gather payload,
// 6.4MB array -> L2-resident). AS/AD/Z/alpha stay fp32 (computed from the
// fp32 GEMM accumulator, so the alpha output is bit-identical to R7).

// ---------------------------------------------------------------------------
// CSR build. R6: scatter was latency-bound on the dependent
// atomicAdd(fill)->store chain. Fix: capture within-dst rank in degree_kernel
// (already pays the random atomic); scatter becomes atomic-free.
__global__ void degree_kernel(const int* __restrict__ ei, int* __restrict__ deg,
                              int* __restrict__ rank) {
    int e = blockIdx.x * blockDim.x + threadIdx.x;
    if (e >= ETOT) return;
    int d = (e < EE) ? ei[EE + e] : (e - EE);
    rank[e] = atomicAdd(&deg[d], 1);
}

// Block-wise exclusive scan (1024/block), Hillis-Steele
__global__ void scan_block_kernel(const int* __restrict__ deg, int* __restrict__ rowstart,
                                  int* __restrict__ bsums) {
    __shared__ int tmp[1024];
    int tid = threadIdx.x;
    int i = blockIdx.x * 1024 + tid;
    int v = (i < NN) ? deg[i] : 0;
    tmp[tid] = v;
    __syncthreads();
    for (int off = 1; off < 1024; off <<= 1) {
        int t = (tid >= off) ? tmp[tid - off] : 0;
        __syncthreads();
        tmp[tid] += t;
        __syncthreads();
    }
    if (i < NN) rowstart[i] = tmp[tid] - v;   // exclusive
    if (tid == 1023) bsums[blockIdx.x] = tmp[tid];
}

__global__ void scan_sums_kernel(int* __restrict__ bsums, int nb) {
    if (threadIdx.x == 0 && blockIdx.x == 0) {
        int acc = 0;
        for (int i = 0; i < nb; ++i) { int t = bsums[i]; bsums[i] = acc; acc += t; }
    }
}

__global__ void add_offsets_kernel(int* __restrict__ rowstart, const int* __restrict__ bsums) {
    int i = blockIdx.x * blockDim.x + threadIdx.x;
    if (i < NN) rowstart[i] += bsums[i >> 10];
}

// Atomic-free scatter: packed int4 entry = single 16B store.
__global__ void scatter_kernel(const int* __restrict__ ei, const int* __restrict__ rowstart,
                               const int* __restrict__ rank, int4* __restrict__ csr) {
    int e = blockIdx.x * blockDim.x + threadIdx.x;
    if (e >= ETOT) return;
    int s, d;
    if (e < EE) { s = ei[e]; d = ei[EE + e]; }
    else        { s = e - EE; d = e - EE; }
    int pos = rowstart[d] + rank[e];
    csr[pos] = make_int4(s, d, e, 0);
}

// ---------------------------------------------------------------------------
// Fused GEMM (h = x @ W^T) + attention dot products per node.
// Block = 256 threads = 4 waves; block tile = 16 nodes; each wave owns 4 rows
// with acc[4] register blocking; col = lane. NN % 16 == 0 so no tail checks.
// sW stride 65: stride-64 put all lanes on one bank (R2: 2.48e7 conflicts).
// R3 NOTE: acc[8]+full unroll spilled (VGPR 256) — keep acc[4] + unroll 4.
// H store is fp16 (R8); AS/AD from the fp32 accumulator.
template <int DD>
__global__ __launch_bounds__(256) void gemm_att_kernel(
    const float* __restrict__ X, const float* __restrict__ W,
    const float* __restrict__ attS, const float* __restrict__ attD,
    __half* __restrict__ H, float* __restrict__ AS, float* __restrict__ AD) {
    __shared__ float sW[DD * 65];   // sW[k*65+c] = W[c*DD+k]
    __shared__ float sX[16][DD];
    int tid = threadIdx.x;
    // Stage W: float4 global loads, padded-stride LDS writes (conflict-free).
    for (int i = tid * 4; i < 64 * DD; i += 1024) {
        int c = i / DD, k = i % DD;
        float4 w = *(const float4*)(W + i);
        sW[(k + 0) * 65 + c] = w.x;
        sW[(k + 1) * 65 + c] = w.y;
        sW[(k + 2) * 65 + c] = w.z;
        sW[(k + 3) * 65 + c] = w.w;
    }
    int base = blockIdx.x * 16;
    const float4* X4 = (const float4*)(X + (size_t)base * DD);
    float4* sX4 = (float4*)(&sX[0][0]);
    for (int i = tid; i < 16 * DD / 4; i += 256) sX4[i] = X4[i];
    __syncthreads();

    int col = tid & 63;
    int wv = tid >> 6;          // 0..3
    int r0 = wv * 4;
    int head = col >> 4;
    float acc[4] = {0.f, 0.f, 0.f, 0.f};
#pragma unroll 4
    for (int k = 0; k < DD; k += 4) {
        float w0 = sW[(k + 0) * 65 + col];
        float w1 = sW[(k + 1) * 65 + col];
        float w2 = sW[(k + 2) * 65 + col];
        float w3 = sW[(k + 3) * 65 + col];
#pragma unroll
        for (int r = 0; r < 4; ++r) {
            float4 xv = *(const float4*)&sX[r0 + r][k];
            acc[r] = fmaf(xv.x, w0, acc[r]);
            acc[r] = fmaf(xv.y, w1, acc[r]);
            acc[r] = fmaf(xv.z, w2, acc[r]);
            acc[r] = fmaf(xv.w, w3, acc[r]);
        }
    }
    float as_c = attS[col];
    float ad_c = attD[col];
#pragma unroll
    for (int r = 0; r < 4; ++r) {
        int node = base + r0 + r;
        H[(size_t)node * 64 + col] = __float2half(acc[r]);
        float vs = acc[r] * as_c;
        float vd = acc[r] * ad_c;
#pragma unroll
        for (int off = 8; off; off >>= 1) {
            vs += __shfl_down(vs, off, 16);
            vd += __shfl_down(vd, off, 16);
        }
        if ((col & 15) == 0) {
            AS[node * 4 + head] = vs;
            AD[node * 4 + head] = vd;
        }
    }
}

// ---------------------------------------------------------------------------
// Per-node aggregation with inline attention weights (R7) and fp16 H gathers
// (R8). One wave per node; lane = head*16 + channel. 4x unrolled independent
// gathers for memory-level parallelism (R4). Fused bias+ReLU+BN epilogue.
// No max-subtraction: logits are O(1) — exp cannot overflow.
template <bool WRITE_Z>
__global__ __launch_bounds__(256) void edge_aggr_kernel(
    const __half* __restrict__ H, const float* __restrict__ AS,
    const float* __restrict__ AD,
    const int* __restrict__ rowstart, const int* __restrict__ deg,
    const int4* __restrict__ csr,
    const float* __restrict__ bias, const float* __restrict__ gamma,
    const float* __restrict__ beta, const float* __restrict__ mean,
    const float* __restrict__ var, float* __restrict__ Hout,
    float* __restrict__ Z) {
    int v = (blockIdx.x * blockDim.x + threadIdx.x) >> 6;
    if (v >= NN) return;
    int lane = threadIdx.x & 63;
    int head = lane >> 4;
    float adv = AD[v * 4 + head];
    int start = rowstart[v];
    int cnt = deg[v];                    // >= 1 (self loop)
    const int4* srow = csr + start;
    float z = 0.f, acc = 0.f;
    int k = 0;
    for (; k + 4 <= cnt; k += 4) {
        int s0 = srow[k + 0].x;
        int s1 = srow[k + 1].x;
        int s2 = srow[k + 2].x;
        int s3 = srow[k + 3].x;
        float a0 = AS[(size_t)s0 * 4 + head];
        float a1 = AS[(size_t)s1 * 4 + head];
        float a2 = AS[(size_t)s2 * 4 + head];
        float a3 = AS[(size_t)s3 * 4 + head];
        float h0 = __half2float(H[(size_t)s0 * 64 + lane]);
        float h1 = __half2float(H[(size_t)s1 * 64 + lane]);
        float h2 = __half2float(H[(size_t)s2 * 64 + lane]);
        float h3 = __half2float(H[(size_t)s3 * 64 + lane]);
        float l0 = a0 + adv; l0 = l0 > 0.f ? l0 : NEGS * l0; float p0 = __expf(l0);
        float l1 = a1 + adv; l1 = l1 > 0.f ? l1 : NEGS * l1; float p1 = __expf(l1);
        float l2 = a2 + adv; l2 = l2 > 0.f ? l2 : NEGS * l2; float p2 = __expf(l2);
        float l3 = a3 + adv; l3 = l3 > 0.f ? l3 : NEGS * l3; float p3 = __expf(l3);
        z += (p0 + p1) + (p2 + p3);
        acc = fmaf(p0, h0, acc);
        acc = fmaf(p1, h1, acc);
        acc = fmaf(p2, h2, acc);
        acc = fmaf(p3, h3, acc);
    }
    for (; k < cnt; ++k) {
        int s = srow[k].x;
        float a = AS[(size_t)s * 4 + head];
        float hv = __half2float(H[(size_t)s * 64 + lane]);
        float l = a + adv; l = l > 0.f ? l : NEGS * l;
        float p = __expf(l);
        z += p;
        acc = fmaf(p, hv, acc);
    }
    if (WRITE_Z && (lane & 15) == 0) Z[v * 4 + head] = z;
    float res = acc / z + bias[lane];
    res = fmaxf(res, 0.f);
    res = gamma[lane] * (res - mean[lane]) * rsqrtf(var[lane] + BNEPS) + beta[lane];
    Hout[(size_t)v * 64 + lane] = res;
}

// ---------------------------------------------------------------------------
// Layer-0 alpha write-back: recompute p from AS/AD (identical formula+inputs
// as aggr => identical values), divide by Z, scatter to eid.
__global__ __launch_bounds__(256) void alpha_kernel(
    const float* __restrict__ AS, const float* __restrict__ AD,
    const float* __restrict__ Z, const int4* __restrict__ csr,
    float* __restrict__ alpha_out) {
    int j = blockIdx.x * blockDim.x + threadIdx.x;
    if (j >= ETOT) return;
    int4 en = csr[j];
    float4 as = *(const float4*)(AS + (size_t)en.x * 4);
    float4 ad = *(const float4*)(AD + (size_t)en.y * 4);
    float4 z4 = *(const float4*)(Z + (size_t)en.y * 4);
    float l;
    float4 a;
    l = as.x + ad.x; l = l > 0.f ? l : NEGS * l; a.x = __expf(l) / z4.x;
    l = as.y + ad.y; l = l > 0.f ? l : NEGS * l; a.y = __expf(l) / z4.y;
    l = as.z + ad.z; l = l > 0.f ? l : NEGS * l; a.z = __expf(l) / z4.z;
    l = as.w + ad.w; l = l > 0.f ? l : NEGS * l; a.w = __expf(l) / z4.w;
    *(float4*)(alpha_out + (size_t)en.z * 4) = a;
}

// ---------------------------------------------------------------------------
// Mean pool over sorted batch ids: one wave per 64-node chunk, local
// accumulation, atomic flush on graph-id change.
__global__ __launch_bounds__(256) void pool_kernel(const float* __restrict__ H,
                                                   const int* __restrict__ batch,
                                                   float* __restrict__ sums,
                                                   int* __restrict__ cnt) {
    int wid = (blockIdx.x * blockDim.x + threadIdx.x) >> 6;
    int lane = threadIdx.x & 63;
    int base = wid * 64;
    if (base >= NN) return;
    int end = min(base + 64, NN);
    int cur = batch[base];
    float acc = 0.f;
    int c0 = 0;
    for (int i = base; i < end; ++i) {
        int g = batch[i];
        if (g != cur) {
            atomicAdd(&sums[cur * 64 + lane], acc);
            if (lane == 0) atomicAdd(&cnt[cur], c0);
            cur = g; acc = 0.f; c0 = 0;
        }
        acc += H[(size_t)i * 64 + lane];
        c0++;
    }
    atomicAdd(&sums[cur * 64 + lane], acc);
    if (lane == 0) atomicAdd(&cnt[cur], c0);
}

__global__ void fc_kernel(const float* __restrict__ sums, const int* __restrict__ cnt,
                          const float* __restrict__ fcW, const float* __restrict__ fcb,
                          float* __restrict__ out) {
    int g = (blockIdx.x * blockDim.x + threadIdx.x) >> 6;
    int lane = threadIdx.x & 63;
    if (g >= NG) return;
    float c = fmaxf((float)cnt[g], 1.f);
    float val = (sums[g * 64 + lane] / c) * fcW[lane];
#pragma unroll
    for (int off = 32; off; off >>= 1) val += __shfl_down(val, off, 64);
    if (lane == 0) out[g] = 1.f / (1.f + expf(-(val + fcb[0])));
}

// ---------------------------------------------------------------------------
extern "C" void kernel_launch(void* const* d_in, const int* in_sizes, int n_in,
                              void* d_out, int out_size, void* d_ws, size_t ws_size,
                              hipStream_t stream) {
    const float* x   = (const float*)d_in[0];
    const int* ei    = (const int*)d_in[1];
    const int* batch = (const int*)d_in[2];
    const float* W[3], *attS[3], *attD[3], *bias[3], *gamma[3], *beta[3], *mean[3], *var[3];
    for (int l = 0; l < 3; ++l) {
        W[l]     = (const float*)d_in[3 + 8 * l + 0];
        attS[l]  = (const float*)d_in[3 + 8 * l + 1];
        attD[l]  = (const float*)d_in[3 + 8 * l + 2];
        bias[l]  = (const float*)d_in[3 + 8 * l + 3];
        gamma[l] = (const float*)d_in[3 + 8 * l + 4];
        beta[l]  = (const float*)d_in[3 + 8 * l + 5];
        mean[l]  = (const float*)d_in[3 + 8 * l + 6];
        var[l]   = (const float*)d_in[3 + 8 * l + 7];
    }
    const float* fcW = (const float*)d_in[27];
    const float* fcb = (const float*)d_in[28];
    float* out = (float*)d_out;               // [128] pooled sigmoid
    float* alpha_out = (float*)d_out + NG;    // [850000*4] layer-0 alpha

    // Workspace carve-up (256B aligned)
    char* p = (char*)d_ws;
    auto carve = [&](size_t bytes) {
        char* q = p;
        p += (bytes + 255) & ~(size_t)255;
        return q;
    };
    __half* hA      = (__half*)carve(sizeof(__half) * NN * 64);
    float* hB       = (float*)carve(sizeof(float) * NN * 64);
    float* AS       = (float*)carve(sizeof(float) * NN * 4);
    float* AD       = (float*)carve(sizeof(float) * NN * 4);
    float* Z        = (float*)carve(sizeof(float) * NN * 4);
    int*   rowstart = (int*)carve(sizeof(int) * NN);
    int*   deg      = (int*)carve(sizeof(int) * NN);
    int*   rank     = (int*)carve(sizeof(int) * ETOT);
    int*   bsums    = (int*)carve(sizeof(int) * 64);
    int4*  csr      = (int4*)carve(sizeof(int4) * ETOT);
    float* psums    = (float*)carve(sizeof(float) * NG * 64);
    int*   pcnt     = (int*)carve(sizeof(int) * NG);

    hipMemsetAsync(deg, 0, sizeof(int) * NN, stream);
    hipMemsetAsync(psums, 0, sizeof(float) * NG * 64, stream);
    hipMemsetAsync(pcnt, 0, sizeof(int) * NG, stream);

    // CSR build
    int nbScan = (NN + 1023) / 1024;
    degree_kernel<<<(ETOT + 255) / 256, 256, 0, stream>>>(ei, deg, rank);
    scan_block_kernel<<<nbScan, 1024, 0, stream>>>(deg, rowstart, bsums);
    scan_sums_kernel<<<1, 64, 0, stream>>>(bsums, nbScan);
    add_offsets_kernel<<<(NN + 255) / 256, 256, 0, stream>>>(rowstart, bsums);
    scatter_kernel<<<(ETOT + 255) / 256, 256, 0, stream>>>(ei, rowstart, rank, csr);

    int edgeBlocks = (NN * 64 + 255) / 256;
    int posBlocks = (ETOT + 255) / 256;
    int gemmBlocks = NN / 16;   // 3125, exact

    // Layer 0 (input dim 128), writes Z then alpha
    gemm_att_kernel<128><<<gemmBlocks, 256, 0, stream>>>(x, W[0], attS[0], attD[0], hA, AS, AD);
    edge_aggr_kernel<true><<<edgeBlocks, 256, 0, stream>>>(
        hA, AS, AD, rowstart, deg, csr,
        bias[0], gamma[0], beta[0], mean[0], var[0], hB, Z);
    alpha_kernel<<<posBlocks, 256, 0, stream>>>(AS, AD, Z, csr, alpha_out);

    // Layer 1
    gemm_att_kernel<64><<<gemmBlocks, 256, 0, stream>>>(hB, W[1], attS[1], attD[1], hA, AS, AD);
    edge_aggr_kernel<false><<<edgeBlocks, 256, 0, stream>>>(
        hA, AS, AD, rowstart, deg, csr,
        bias[1], gamma[1], beta[1], mean[1], var[1], hB, nullptr);

    // Layer 2
    gemm_att_kernel<64><<<gemmBlocks, 256, 0, stream>>>(hB, W[2], attS[2], attD[2], hA, AS, AD);
    edge_aggr_kernel<false><<<edgeBlocks, 256, 0, stream>>>(
        hA, AS, AD, rowstart, deg, csr,
        bias[2], gamma[2], beta[2], mean[2], var[2], hB, nullptr);

    // Pool + FC
    int poolWaves = (NN + 63) / 64;
    pool_kernel<<<(poolWaves * 64 + 255) / 256, 256, 0, stream>>>(hB, batch, psums, pcnt);
    fc_kernel<<<(NG * 64 + 255) / 256, 256, 0, stream>>>(psums, pcnt, fcW, fcb, out);
}

// Round 9
// 402.625 us; speedup vs baseline: 2.7600x; 1.0569x over previous
//
#include <hip/hip_runtime.h>
#include <hip/hip_fp16.h>
#include <math.h>

// Problem constants (match reference)
#define NN     50000
#define EE     800000
#define ETOT   (EE + NN)      // edges + self loops = 850000
#define INDIM  128
#define HEADS  4
#define NG     128
#define NEGS   0.2f
#define BNEPS  1e-5f

typedef _Float16 half8 __attribute__((ext_vector_type(8)));
typedef float floatx4 __attribute__((ext_vector_type(4)));

// R9: GEMM moved to MFMA (mfma_f32_16x16x32_f16). R8's VALU gemm was
// LDS-throughput-bound (~2300 LDS cyc vs 1024 FMA cyc per 4 nodes, 19 TF).
// fp16 A/B fragments load directly from global (no LDS at all); fp32 acc;
// AS/AD computed from fp32 acc. x and W are converted to fp16 once per launch.

// ---------------------------------------------------------------------------
// CSR build. R6: rank captured in degree_kernel (already pays the random
// atomic); scatter is atomic-free. R5: packed int4 entry = single 16B store.
__global__ void degree_kernel(const int* __restrict__ ei, int* __restrict__ deg,
                              int* __restrict__ rank) {
    int e = blockIdx.x * blockDim.x + threadIdx.x;
    if (e >= ETOT) return;
    int d = (e < EE) ? ei[EE + e] : (e - EE);
    rank[e] = atomicAdd(&deg[d], 1);
}

__global__ void scan_block_kernel(const int* __restrict__ deg, int* __restrict__ rowstart,
                                  int* __restrict__ bsums) {
    __shared__ int tmp[1024];
    int tid = threadIdx.x;
    int i = blockIdx.x * 1024 + tid;
    int v = (i < NN) ? deg[i] : 0;
    tmp[tid] = v;
    __syncthreads();
    for (int off = 1; off < 1024; off <<= 1) {
        int t = (tid >= off) ? tmp[tid - off] : 0;
        __syncthreads();
        tmp[tid] += t;
        __syncthreads();
    }
    if (i < NN) rowstart[i] = tmp[tid] - v;   // exclusive
    if (tid == 1023) bsums[blockIdx.x] = tmp[tid];
}

__global__ void scan_sums_kernel(int* __restrict__ bsums, int nb) {
    if (threadIdx.x == 0 && blockIdx.x == 0) {
        int acc = 0;
        for (int i = 0; i < nb; ++i) { int t = bsums[i]; bsums[i] = acc; acc += t; }
    }
}

__global__ void add_offsets_kernel(int* __restrict__ rowstart, const int* __restrict__ bsums) {
    int i = blockIdx.x * blockDim.x + threadIdx.x;
    if (i < NN) rowstart[i] += bsums[i >> 10];
}

__global__ void scatter_kernel(const int* __restrict__ ei, const int* __restrict__ rowstart,
                               const int* __restrict__ rank, int4* __restrict__ csr) {
    int e = blockIdx.x * blockDim.x + threadIdx.x;
    if (e >= ETOT) return;
    int s, d;
    if (e < EE) { s = ei[e]; d = ei[EE + e]; }
    else        { s = e - EE; d = e - EE; }
    int pos = rowstart[d] + rank[e];
    csr[pos] = make_int4(s, d, e, 0);
}

// ---------------------------------------------------------------------------
// fp32 -> fp16 converts (once per launch).
__global__ __launch_bounds__(256) void cvt_x_kernel(const float* __restrict__ in,
                                                    _Float16* __restrict__ outp) {
    int i = blockIdx.x * blockDim.x + threadIdx.x;     // x8 floats
    if (i >= NN * INDIM / 8) return;
    float4 v0 = *(const float4*)(in + (size_t)i * 8);
    float4 v1 = *(const float4*)(in + (size_t)i * 8 + 4);
    half8 o;
    o[0] = (_Float16)v0.x; o[1] = (_Float16)v0.y;
    o[2] = (_Float16)v0.z; o[3] = (_Float16)v0.w;
    o[4] = (_Float16)v1.x; o[5] = (_Float16)v1.y;
    o[6] = (_Float16)v1.z; o[7] = (_Float16)v1.w;
    *(half8*)(outp + (size_t)i * 8) = o;
}

// All three layers' W: 64*128 + 64*64 + 64*64 = 16384 elements.
__global__ __launch_bounds__(256) void cvt_w_kernel(const float* __restrict__ W0,
                                                    const float* __restrict__ W1,
                                                    const float* __restrict__ W2,
                                                    _Float16* __restrict__ Wh) {
    int i = blockIdx.x * blockDim.x + threadIdx.x;
    if (i >= 16384) return;
    float v = (i < 8192) ? W0[i] : ((i < 12288) ? W1[i - 8192] : W2[i - 12288]);
    Wh[i] = (_Float16)v;
}

// ---------------------------------------------------------------------------
// MFMA GEMM (h = x @ W^T) + attention dots. Block = 4 waves; each wave owns
// 16 nodes x 64 cols = 4 col-tiles of 16x16, K in 32-chunks.
// A frag: X[wbase + (lane&15)][kb*32 + quad*8 ..+8]  (A[m=lane&15][k=quad*8+j])
// B frag: W[t*16 + (lane&15)][kb*32 + quad*8 ..+8]   (same K-contiguous shape)
// C/D:   node = wbase + quad*4 + reg, col = t*16 + (lane&15)
// AS/AD reduction: width-16 shfl = 16 channels of head t for one node (quad).
template <int DD>
__global__ __launch_bounds__(256) void gemm_att_kernel(
    const _Float16* __restrict__ X, const _Float16* __restrict__ Wh,
    const float* __restrict__ attS, const float* __restrict__ attD,
    _Float16* __restrict__ H, float* __restrict__ AS, float* __restrict__ AD) {
    constexpr int KB = DD / 32;
    int tid = threadIdx.x;
    int wv = tid >> 6;
    int lane = tid & 63;
    int quad = lane >> 4;
    int n = lane & 15;
    int wbase = blockIdx.x * 64 + wv * 16;

    int arow = wbase + n;
    if (arow >= NN) arow = NN - 1;          // clamp (stores are guarded)
    half8 a[KB];
#pragma unroll
    for (int kb = 0; kb < KB; ++kb)
        a[kb] = *(const half8*)(X + (size_t)arow * DD + kb * 32 + quad * 8);

    floatx4 c[4];
#pragma unroll
    for (int t = 0; t < 4; ++t) {
        floatx4 acc = {0.f, 0.f, 0.f, 0.f};
#pragma unroll
        for (int kb = 0; kb < KB; ++kb) {
            half8 b = *(const half8*)(Wh + (size_t)(t * 16 + n) * DD + kb * 32 + quad * 8);
            acc = __builtin_amdgcn_mfma_f32_16x16x32_f16(a[kb], b, acc, 0, 0, 0);
        }
        c[t] = acc;
    }

    float as_l[4], ad_l[4];
#pragma unroll
    for (int t = 0; t < 4; ++t) {
        as_l[t] = attS[t * 16 + n];
        ad_l[t] = attD[t * 16 + n];
    }
#pragma unroll
    for (int r = 0; r < 4; ++r) {
        int node = wbase + quad * 4 + r;
        bool ok = node < NN;
#pragma unroll
        for (int t = 0; t < 4; ++t) {
            float h = c[t][r];
            if (ok) H[(size_t)node * 64 + t * 16 + n] = (_Float16)h;
            float vs = h * as_l[t];
            float vd = h * ad_l[t];
#pragma unroll
            for (int off = 8; off; off >>= 1) {
                vs += __shfl_down(vs, off, 16);
                vd += __shfl_down(vd, off, 16);
            }
            if (ok && n == 0) {
                AS[node * 4 + t] = vs;
                AD[node * 4 + t] = vd;
            }
        }
    }
}

// ---------------------------------------------------------------------------
// Per-node aggregation: inline attention weights (R7), fp16 H gathers (R8),
// 4x unrolled independent gathers (R4). Output now fp16 (feeds next MFMA gemm
// / pool). Fused bias+ReLU+BN epilogue. No max-subtraction (logits O(1)).
template <bool WRITE_Z>
__global__ __launch_bounds__(256) void edge_aggr_kernel(
    const __half* __restrict__ H, const float* __restrict__ AS,
    const float* __restrict__ AD,
    const int* __restrict__ rowstart, const int* __restrict__ deg,
    const int4* __restrict__ csr,
    const float* __restrict__ bias, const float* __restrict__ gamma,
    const float* __restrict__ beta, const float* __restrict__ mean,
    const float* __restrict__ var, __half* __restrict__ Hout,
    float* __restrict__ Z) {
    int v = (blockIdx.x * blockDim.x + threadIdx.x) >> 6;
    if (v >= NN) return;
    int lane = threadIdx.x & 63;
    int head = lane >> 4;
    float adv = AD[v * 4 + head];
    int start = rowstart[v];
    int cnt = deg[v];                    // >= 1 (self loop)
    const int4* srow = csr + start;
    float z = 0.f, acc = 0.f;
    int k = 0;
    for (; k + 4 <= cnt; k += 4) {
        int s0 = srow[k + 0].x;
        int s1 = srow[k + 1].x;
        int s2 = srow[k + 2].x;
        int s3 = srow[k + 3].x;
        float a0 = AS[(size_t)s0 * 4 + head];
        float a1 = AS[(size_t)s1 * 4 + head];
        float a2 = AS[(size_t)s2 * 4 + head];
        float a3 = AS[(size_t)s3 * 4 + head];
        float h0 = __half2float(H[(size_t)s0 * 64 + lane]);
        float h1 = __half2float(H[(size_t)s1 * 64 + lane]);
        float h2 = __half2float(H[(size_t)s2 * 64 + lane]);
        float h3 = __half2float(H[(size_t)s3 * 64 + lane]);
        float l0 = a0 + adv; l0 = l0 > 0.f ? l0 : NEGS * l0; float p0 = __expf(l0);
        float l1 = a1 + adv; l1 = l1 > 0.f ? l1 : NEGS * l1; float p1 = __expf(l1);
        float l2 = a2 + adv; l2 = l2 > 0.f ? l2 : NEGS * l2; float p2 = __expf(l2);
        float l3 = a3 + adv; l3 = l3 > 0.f ? l3 : NEGS * l3; float p3 = __expf(l3);
        z += (p0 + p1) + (p2 + p3);
        acc = fmaf(p0, h0, acc);
        acc = fmaf(p1, h1, acc);
        acc = fmaf(p2, h2, acc);
        acc = fmaf(p3, h3, acc);
    }
    for (; k < cnt; ++k) {
        int s = srow[k].x;
        float a = AS[(size_t)s * 4 + head];
        float hv = __half2float(H[(size_t)s * 64 + lane]);
        float l = a + adv; l = l > 0.f ? l : NEGS * l;
        float p = __expf(l);
        z += p;
        acc = fmaf(p, hv, acc);
    }
    if (WRITE_Z && (lane & 15) == 0) Z[v * 4 + head] = z;
    float res = acc / z + bias[lane];
    res = fmaxf(res, 0.f);
    res = gamma[lane] * (res - mean[lane]) * rsqrtf(var[lane] + BNEPS) + beta[lane];
    Hout[(size_t)v * 64 + lane] = __float2half(res);
}

// ---------------------------------------------------------------------------
// Layer-0 alpha write-back: recompute p from AS/AD (identical formula+inputs
// as aggr => identical values), divide by Z, scatter to eid.
__global__ __launch_bounds__(256) void alpha_kernel(
    const float* __restrict__ AS, const float* __restrict__ AD,
    const float* __restrict__ Z, const int4* __restrict__ csr,
    float* __restrict__ alpha_out) {
    int j = blockIdx.x * blockDim.x + threadIdx.x;
    if (j >= ETOT) return;
    int4 en = csr[j];
    float4 as = *(const float4*)(AS + (size_t)en.x * 4);
    float4 ad = *(const float4*)(AD + (size_t)en.y * 4);
    float4 z4 = *(const float4*)(Z + (size_t)en.y * 4);
    float l;
    float4 a;
    l = as.x + ad.x; l = l > 0.f ? l : NEGS * l; a.x = __expf(l) / z4.x;
    l = as.y + ad.y; l = l > 0.f ? l : NEGS * l; a.y = __expf(l) / z4.y;
    l = as.z + ad.z; l = l > 0.f ? l : NEGS * l; a.z = __expf(l) / z4.z;
    l = as.w + ad.w; l = l > 0.f ? l : NEGS * l; a.w = __expf(l) / z4.w;
    *(float4*)(alpha_out + (size_t)en.z * 4) = a;
}

// ---------------------------------------------------------------------------
// Mean pool over sorted batch ids (input now fp16): one wave per 64-node
// chunk, local accumulation, atomic flush on graph-id change.
__global__ __launch_bounds__(256) void pool_kernel(const __half* __restrict__ H,
                                                   const int* __restrict__ batch,
                                                   float* __restrict__ sums,
                                                   int* __restrict__ cnt) {
    int wid = (blockIdx.x * blockDim.x + threadIdx.x) >> 6;
    int lane = threadIdx.x & 63;
    int base = wid * 64;
    if (base >= NN) return;
    int end = min(base + 64, NN);
    int cur = batch[base];
    float acc = 0.f;
    int c0 = 0;
    for (int i = base; i < end; ++i) {
        int g = batch[i];
        if (g != cur) {
            atomicAdd(&sums[cur * 64 + lane], acc);
            if (lane == 0) atomicAdd(&cnt[cur], c0);
            cur = g; acc = 0.f; c0 = 0;
        }
        acc += __half2float(H[(size_t)i * 64 + lane]);
        c0++;
    }
    atomicAdd(&sums[cur * 64 + lane], acc);
    if (lane == 0) atomicAdd(&cnt[cur], c0);
}

__global__ void fc_kernel(const float* __restrict__ sums, const int* __restrict__ cnt,
                          const float* __restrict__ fcW, const float* __restrict__ fcb,
                          float* __restrict__ out) {
    int g = (blockIdx.x * blockDim.x + threadIdx.x) >> 6;
    int lane = threadIdx.x & 63;
    if (g >= NG) return;
    float c = fmaxf((float)cnt[g], 1.f);
    float val = (sums[g * 64 + lane] / c) * fcW[lane];
#pragma unroll
    for (int off = 32; off; off >>= 1) val += __shfl_down(val, off, 64);
    if (lane == 0) out[g] = 1.f / (1.f + expf(-(val + fcb[0])));
}

// ---------------------------------------------------------------------------
extern "C" void kernel_launch(void* const* d_in, const int* in_sizes, int n_in,
                              void* d_out, int out_size, void* d_ws, size_t ws_size,
                              hipStream_t stream) {
    const float* x   = (const float*)d_in[0];
    const int* ei    = (const int*)d_in[1];
    const int* batch = (const int*)d_in[2];
    const float* W[3], *attS[3], *attD[3], *bias[3], *gamma[3], *beta[3], *mean[3], *var[3];
    for (int l = 0; l < 3; ++l) {
        W[l]     = (const float*)d_in[3 + 8 * l + 0];
        attS[l]  = (const float*)d_in[3 + 8 * l + 1];
        attD[l]  = (const float*)d_in[3 + 8 * l + 2];
        bias[l]  = (const float*)d_in[3 + 8 * l + 3];
        gamma[l] = (const float*)d_in[3 + 8 * l + 4];
        beta[l]  = (const float*)d_in[3 + 8 * l + 5];
        mean[l]  = (const float*)d_in[3 + 8 * l + 6];
        var[l]   = (const float*)d_in[3 + 8 * l + 7];
    }
    const float* fcW = (const float*)d_in[27];
    const float* fcb = (const float*)d_in[28];
    float* out = (float*)d_out;               // [128] pooled sigmoid
    float* alpha_out = (float*)d_out + NG;    // [850000*4] layer-0 alpha

    // Workspace carve-up (256B aligned)
    char* p = (char*)d_ws;
    auto carve = [&](size_t bytes) {
        char* q = p;
        p += (bytes + 255) & ~(size_t)255;
        return q;
    };
    _Float16* Xh    = (_Float16*)carve(sizeof(_Float16) * NN * INDIM);
    _Float16* Wh    = (_Float16*)carve(sizeof(_Float16) * 16384);
    _Float16* Hh    = (_Float16*)carve(sizeof(_Float16) * NN * 64);  // gemm out
    _Float16* Hn    = (_Float16*)carve(sizeof(_Float16) * NN * 64);  // aggr out
    float* AS       = (float*)carve(sizeof(float) * NN * 4);
    float* AD       = (float*)carve(sizeof(float) * NN * 4);
    float* Z        = (float*)carve(sizeof(float) * NN * 4);
    int*   rowstart = (int*)carve(sizeof(int) * NN);
    int*   deg      = (int*)carve(sizeof(int) * NN);
    int*   rank     = (int*)carve(sizeof(int) * ETOT);
    int*   bsums    = (int*)carve(sizeof(int) * 64);
    int4*  csr      = (int4*)carve(sizeof(int4) * ETOT);
    float* psums    = (float*)carve(sizeof(float) * NG * 64);
    int*   pcnt     = (int*)carve(sizeof(int) * NG);

    hipMemsetAsync(deg, 0, sizeof(int) * NN, stream);
    hipMemsetAsync(psums, 0, sizeof(float) * NG * 64, stream);
    hipMemsetAsync(pcnt, 0, sizeof(int) * NG, stream);

    // fp16 converts
    cvt_x_kernel<<<(NN * INDIM / 8 + 255) / 256, 256, 0, stream>>>(x, Xh);
    cvt_w_kernel<<<64, 256, 0, stream>>>(W[0], W[1], W[2], Wh);

    // CSR build
    int nbScan = (NN + 1023) / 1024;
    degree_kernel<<<(ETOT + 255) / 256, 256, 0, stream>>>(ei, deg, rank);
    scan_block_kernel<<<nbScan, 1024, 0, stream>>>(deg, rowstart, bsums);
    scan_sums_kernel<<<1, 64, 0, stream>>>(bsums, nbScan);
    add_offsets_kernel<<<(NN + 255) / 256, 256, 0, stream>>>(rowstart, bsums);
    scatter_kernel<<<(ETOT + 255) / 256, 256, 0, stream>>>(ei, rowstart, rank, csr);

    int edgeBlocks = (NN * 64 + 255) / 256;
    int posBlocks = (ETOT + 255) / 256;
    int gemmBlocks = (NN + 63) / 64;   // 782

    // Layer 0 (K=128), writes Z then alpha
    gemm_att_kernel<128><<<gemmBlocks, 256, 0, stream>>>(Xh, Wh, attS[0], attD[0],
                                                         Hh, AS, AD);
    edge_aggr_kernel<true><<<edgeBlocks, 256, 0, stream>>>(
        (const __half*)Hh, AS, AD, rowstart, deg, csr,
        bias[0], gamma[0], beta[0], mean[0], var[0], (__half*)Hn, Z);
    alpha_kernel<<<posBlocks, 256, 0, stream>>>(AS, AD, Z, csr, alpha_out);

    // Layer 1 (K=64)
    gemm_att_kernel<64><<<gemmBlocks, 256, 0, stream>>>(Hn, Wh + 8192, attS[1], attD[1],
                                                        Hh, AS, AD);
    edge_aggr_kernel<false><<<edgeBlocks, 256, 0, stream>>>(
        (const __half*)Hh, AS, AD, rowstart, deg, csr,
        bias[1], gamma[1], beta[1], mean[1], var[1], (__half*)Hn, nullptr);

    // Layer 2 (K=64)
    gemm_att_kernel<64><<<gemmBlocks, 256, 0, stream>>>(Hn, Wh + 12288, attS[2], attD[2],
                                                        Hh, AS, AD);
    edge_aggr_kernel<false><<<edgeBlocks, 256, 0, stream>>>(
        (const __half*)Hh, AS, AD, rowstart, deg, csr,
        bias[2], gamma[2], beta[2], mean[2], var[2], (__half*)Hn, nullptr);

    // Pool + FC
    int poolWaves = (NN + 63) / 64;
    pool_kernel<<<(poolWaves * 64 + 255) / 256, 256, 0, stream>>>(
        (const __half*)Hn, batch, psums, pcnt);
    fc_kernel<<<(NG * 64 + 255) / 256, 256, 0, stream>>>(psums, pcnt, fcW, fcb, out);
}

// Round 10
// 380.117 us; speedup vs baseline: 2.9234x; 1.0592x over previous
//
#include <hip/hip_runtime.h>
#include <hip/hip_fp16.h>
#include <math.h>

// Problem constants (match reference)
#define NN     50000
#define EE     800000
#define ETOT   (EE + NN)      // edges + self loops = 850000
#define INDIM  128
#define HEADS  4
#define NG     128
#define NEGS   0.2f
#define BNEPS  1e-5f

typedef _Float16 half8 __attribute__((ext_vector_type(8)));
typedef _Float16 half2v __attribute__((ext_vector_type(2)));
typedef float floatx4 __attribute__((ext_vector_type(4)));

// R9: GEMM on MFMA (mfma_f32_16x16x32_f16), fragments direct from global.
// R10: edge_aggr half-wave edge pairing — each 32-lane half serves its own
// edge, lanes cover 2 channels via fp16x2 loads. Same gather bytes, HALF the
// gather instructions and serial loop length; 8 edges in flight with the
// 4-deep unroll. Cross-half combine = one shfl_xor(32).

// ---------------------------------------------------------------------------
// CSR build. R6: rank captured in degree_kernel (already pays the random
// atomic); scatter is atomic-free. R5: packed int4 entry = single 16B store.
__global__ void degree_kernel(const int* __restrict__ ei, int* __restrict__ deg,
                              int* __restrict__ rank) {
    int e = blockIdx.x * blockDim.x + threadIdx.x;
    if (e >= ETOT) return;
    int d = (e < EE) ? ei[EE + e] : (e - EE);
    rank[e] = atomicAdd(&deg[d], 1);
}

__global__ void scan_block_kernel(const int* __restrict__ deg, int* __restrict__ rowstart,
                                  int* __restrict__ bsums) {
    __shared__ int tmp[1024];
    int tid = threadIdx.x;
    int i = blockIdx.x * 1024 + tid;
    int v = (i < NN) ? deg[i] : 0;
    tmp[tid] = v;
    __syncthreads();
    for (int off = 1; off < 1024; off <<= 1) {
        int t = (tid >= off) ? tmp[tid - off] : 0;
        __syncthreads();
        tmp[tid] += t;
        __syncthreads();
    }
    if (i < NN) rowstart[i] = tmp[tid] - v;   // exclusive
    if (tid == 1023) bsums[blockIdx.x] = tmp[tid];
}

__global__ void scan_sums_kernel(int* __restrict__ bsums, int nb) {
    if (threadIdx.x == 0 && blockIdx.x == 0) {
        int acc = 0;
        for (int i = 0; i < nb; ++i) { int t = bsums[i]; bsums[i] = acc; acc += t; }
    }
}

__global__ void add_offsets_kernel(int* __restrict__ rowstart, const int* __restrict__ bsums) {
    int i = blockIdx.x * blockDim.x + threadIdx.x;
    if (i < NN) rowstart[i] += bsums[i >> 10];
}

__global__ void scatter_kernel(const int* __restrict__ ei, const int* __restrict__ rowstart,
                               const int* __restrict__ rank, int4* __restrict__ csr) {
    int e = blockIdx.x * blockDim.x + threadIdx.x;
    if (e >= ETOT) return;
    int s, d;
    if (e < EE) { s = ei[e]; d = ei[EE + e]; }
    else        { s = e - EE; d = e - EE; }
    int pos = rowstart[d] + rank[e];
    csr[pos] = make_int4(s, d, e, 0);
}

// ---------------------------------------------------------------------------
// Zero-init deg / psums / pcnt in one launch (replaces 3 hipMemsetAsync).
__global__ __launch_bounds__(256) void zero_kernel(int* __restrict__ deg,
                                                   float* __restrict__ psums,
                                                   int* __restrict__ pcnt) {
    int i = blockIdx.x * blockDim.x + threadIdx.x;
    if (i < NN) deg[i] = 0;
    else if (i < NN + NG * 64) psums[i - NN] = 0.f;
    else if (i < NN + NG * 64 + NG) pcnt[i - NN - NG * 64] = 0;
}

// fp32 -> fp16 converts for X (NN*128) and all three W (16384 elems), fused.
#define NX8 (NN * INDIM / 8)
__global__ __launch_bounds__(256) void cvt_kernel(const float* __restrict__ x,
                                                  const float* __restrict__ W0,
                                                  const float* __restrict__ W1,
                                                  const float* __restrict__ W2,
                                                  _Float16* __restrict__ Xh,
                                                  _Float16* __restrict__ Wh) {
    int i = blockIdx.x * blockDim.x + threadIdx.x;     // x8 floats
    if (i < NX8) {
        float4 v0 = *(const float4*)(x + (size_t)i * 8);
        float4 v1 = *(const float4*)(x + (size_t)i * 8 + 4);
        half8 o;
        o[0] = (_Float16)v0.x; o[1] = (_Float16)v0.y;
        o[2] = (_Float16)v0.z; o[3] = (_Float16)v0.w;
        o[4] = (_Float16)v1.x; o[5] = (_Float16)v1.y;
        o[6] = (_Float16)v1.z; o[7] = (_Float16)v1.w;
        *(half8*)(Xh + (size_t)i * 8) = o;
    } else if (i < NX8 + 2048) {
        int wi = (i - NX8) * 8;            // 8-groups never straddle W arrays
#pragma unroll
        for (int j = 0; j < 8; ++j) {
            int idx = wi + j;
            float v = (idx < 8192) ? W0[idx]
                    : ((idx < 12288) ? W1[idx - 8192] : W2[idx - 12288]);
            Wh[idx] = (_Float16)v;
        }
    }
}

// ---------------------------------------------------------------------------
// MFMA GEMM (h = x @ W^T) + attention dots. Block = 4 waves; each wave owns
// 16 nodes x 64 cols = 4 col-tiles of 16x16, K in 32-chunks.
// A frag: X[wbase + (lane&15)][kb*32 + quad*8 ..+8]; B frag same shape on W.
// C/D: node = wbase + quad*4 + reg, col = t*16 + (lane&15).
template <int DD>
__global__ __launch_bounds__(256) void gemm_att_kernel(
    const _Float16* __restrict__ X, const _Float16* __restrict__ Wh,
    const float* __restrict__ attS, const float* __restrict__ attD,
    _Float16* __restrict__ H, float* __restrict__ AS, float* __restrict__ AD) {
    constexpr int KB = DD / 32;
    int tid = threadIdx.x;
    int wv = tid >> 6;
    int lane = tid & 63;
    int quad = lane >> 4;
    int n = lane & 15;
    int wbase = blockIdx.x * 64 + wv * 16;

    int arow = wbase + n;
    if (arow >= NN) arow = NN - 1;          // clamp (stores are guarded)
    half8 a[KB];
#pragma unroll
    for (int kb = 0; kb < KB; ++kb)
        a[kb] = *(const half8*)(X + (size_t)arow * DD + kb * 32 + quad * 8);

    floatx4 c[4];
#pragma unroll
    for (int t = 0; t < 4; ++t) {
        floatx4 acc = {0.f, 0.f, 0.f, 0.f};
#pragma unroll
        for (int kb = 0; kb < KB; ++kb) {
            half8 b = *(const half8*)(Wh + (size_t)(t * 16 + n) * DD + kb * 32 + quad * 8);
            acc = __builtin_amdgcn_mfma_f32_16x16x32_f16(a[kb], b, acc, 0, 0, 0);
        }
        c[t] = acc;
    }

    float as_l[4], ad_l[4];
#pragma unroll
    for (int t = 0; t < 4; ++t) {
        as_l[t] = attS[t * 16 + n];
        ad_l[t] = attD[t * 16 + n];
    }
#pragma unroll
    for (int r = 0; r < 4; ++r) {
        int node = wbase + quad * 4 + r;
        bool ok = node < NN;
#pragma unroll
        for (int t = 0; t < 4; ++t) {
            float h = c[t][r];
            if (ok) H[(size_t)node * 64 + t * 16 + n] = (_Float16)h;
            float vs = h * as_l[t];
            float vd = h * ad_l[t];
#pragma unroll
            for (int off = 8; off; off >>= 1) {
                vs += __shfl_down(vs, off, 16);
                vd += __shfl_down(vd, off, 16);
            }
            if (ok && n == 0) {
                AS[node * 4 + t] = vs;
                AD[node * 4 + t] = vd;
            }
        }
    }
}

// ---------------------------------------------------------------------------
// Per-node aggregation, half-wave edge pairing (R10).
// half = lane>>5 picks which edge of a pair this half-wave serves; each lane
// covers 2 channels (ch2 = (lane&31)*2) via fp16x2 gathers. Main loop: 4
// pair-iterations = 8 edges in flight. Cross-half combine: shfl_xor(32).
// Inline attention weights (R7); no max-subtraction (logits O(1)).
template <bool WRITE_Z>
__global__ __launch_bounds__(256) void edge_aggr_kernel(
    const _Float16* __restrict__ H, const float* __restrict__ AS,
    const float* __restrict__ AD,
    const int* __restrict__ rowstart, const int* __restrict__ deg,
    const int4* __restrict__ csr,
    const float* __restrict__ bias, const float* __restrict__ gamma,
    const float* __restrict__ beta, const float* __restrict__ mean,
    const float* __restrict__ var, _Float16* __restrict__ Hout,
    float* __restrict__ Z) {
    int v = (blockIdx.x * blockDim.x + threadIdx.x) >> 6;
    if (v >= NN) return;
    int lane = threadIdx.x & 63;
    int half = lane >> 5;
    int l32 = lane & 31;
    int head = l32 >> 3;
    int ch2 = l32 * 2;
    float adv = AD[v * 4 + head];
    int start = rowstart[v];
    int cnt = deg[v];                    // >= 1 (self loop)
    const int4* srow = csr + start;
    float z = 0.f, acc0 = 0.f, acc1 = 0.f;
    int k = 0;
    for (; k + 8 <= cnt; k += 8) {
        int s0 = srow[k + 0 + half].x;
        int s1 = srow[k + 2 + half].x;
        int s2 = srow[k + 4 + half].x;
        int s3 = srow[k + 6 + half].x;
        float a0 = AS[(size_t)s0 * 4 + head];
        float a1 = AS[(size_t)s1 * 4 + head];
        float a2 = AS[(size_t)s2 * 4 + head];
        float a3 = AS[(size_t)s3 * 4 + head];
        half2v h0 = *(const half2v*)(H + (size_t)s0 * 64 + ch2);
        half2v h1 = *(const half2v*)(H + (size_t)s1 * 64 + ch2);
        half2v h2 = *(const half2v*)(H + (size_t)s2 * 64 + ch2);
        half2v h3 = *(const half2v*)(H + (size_t)s3 * 64 + ch2);
        float l0 = a0 + adv; l0 = l0 > 0.f ? l0 : NEGS * l0; float p0 = __expf(l0);
        float l1 = a1 + adv; l1 = l1 > 0.f ? l1 : NEGS * l1; float p1 = __expf(l1);
        float l2 = a2 + adv; l2 = l2 > 0.f ? l2 : NEGS * l2; float p2 = __expf(l2);
        float l3 = a3 + adv; l3 = l3 > 0.f ? l3 : NEGS * l3; float p3 = __expf(l3);
        z += (p0 + p1) + (p2 + p3);
        acc0 = fmaf(p0, (float)h0[0], acc0); acc1 = fmaf(p0, (float)h0[1], acc1);
        acc0 = fmaf(p1, (float)h1[0], acc0); acc1 = fmaf(p1, (float)h1[1], acc1);
        acc0 = fmaf(p2, (float)h2[0], acc0); acc1 = fmaf(p2, (float)h2[1], acc1);
        acc0 = fmaf(p3, (float)h3[0], acc0); acc1 = fmaf(p3, (float)h3[1], acc1);
    }
    for (; k < cnt; k += 2) {
        int idx = k + half;
        if (idx < cnt) {
            int s = srow[idx].x;
            float a = AS[(size_t)s * 4 + head];
            half2v hv = *(const half2v*)(H + (size_t)s * 64 + ch2);
            float l = a + adv; l = l > 0.f ? l : NEGS * l;
            float p = __expf(l);
            z += p;
            acc0 = fmaf(p, (float)hv[0], acc0);
            acc1 = fmaf(p, (float)hv[1], acc1);
        }
    }
    // combine the two half-wave partial sums
    z    += __shfl_xor(z, 32);
    acc0 += __shfl_xor(acc0, 32);
    acc1 += __shfl_xor(acc1, 32);
    if (half == 0) {
        if (WRITE_Z && (l32 & 7) == 0) Z[v * 4 + head] = z;
        float2 bi = *(const float2*)(bias + ch2);
        float2 ga = *(const float2*)(gamma + ch2);
        float2 be = *(const float2*)(beta + ch2);
        float2 mu = *(const float2*)(mean + ch2);
        float2 va = *(const float2*)(var + ch2);
        float r0 = fmaxf(acc0 / z + bi.x, 0.f);
        float r1 = fmaxf(acc1 / z + bi.y, 0.f);
        r0 = ga.x * (r0 - mu.x) * rsqrtf(va.x + BNEPS) + be.x;
        r1 = ga.y * (r1 - mu.y) * rsqrtf(va.y + BNEPS) + be.y;
        half2v o;
        o[0] = (_Float16)r0;
        o[1] = (_Float16)r1;
        *(half2v*)(Hout + (size_t)v * 64 + ch2) = o;
    }
}

// ---------------------------------------------------------------------------
// Layer-0 alpha write-back: recompute p from AS/AD (identical formula+inputs
// as aggr => identical values), divide by Z, scatter to eid.
__global__ __launch_bounds__(256) void alpha_kernel(
    const float* __restrict__ AS, const float* __restrict__ AD,
    const float* __restrict__ Z, const int4* __restrict__ csr,
    float* __restrict__ alpha_out) {
    int j = blockIdx.x * blockDim.x + threadIdx.x;
    if (j >= ETOT) return;
    int4 en = csr[j];
    float4 as = *(const float4*)(AS + (size_t)en.x * 4);
    float4 ad = *(const float4*)(AD + (size_t)en.y * 4);
    float4 z4 = *(const float4*)(Z + (size_t)en.y * 4);
    float l;
    float4 a;
    l = as.x + ad.x; l = l > 0.f ? l : NEGS * l; a.x = __expf(l) / z4.x;
    l = as.y + ad.y; l = l > 0.f ? l : NEGS * l; a.y = __expf(l) / z4.y;
    l = as.z + ad.z; l = l > 0.f ? l : NEGS * l; a.z = __expf(l) / z4.z;
    l = as.w + ad.w; l = l > 0.f ? l : NEGS * l; a.w = __expf(l) / z4.w;
    *(float4*)(alpha_out + (size_t)en.z * 4) = a;
}

// ---------------------------------------------------------------------------
// Mean pool over sorted batch ids (fp16 input): one wave per 64-node chunk,
// local accumulation, atomic flush on graph-id change.
__global__ __launch_bounds__(256) void pool_kernel(const __half* __restrict__ H,
                                                   const int* __restrict__ batch,
                                                   float* __restrict__ sums,
                                                   int* __restrict__ cnt) {
    int wid = (blockIdx.x * blockDim.x + threadIdx.x) >> 6;
    int lane = threadIdx.x & 63;
    int base = wid * 64;
    if (base >= NN) return;
    int end = min(base + 64, NN);
    int cur = batch[base];
    float acc = 0.f;
    int c0 = 0;
    for (int i = base; i < end; ++i) {
        int g = batch[i];
        if (g != cur) {
            atomicAdd(&sums[cur * 64 + lane], acc);
            if (lane == 0) atomicAdd(&cnt[cur], c0);
            cur = g; acc = 0.f; c0 = 0;
        }
        acc += __half2float(H[(size_t)i * 64 + lane]);
        c0++;
    }
    atomicAdd(&sums[cur * 64 + lane], acc);
    if (lane == 0) atomicAdd(&cnt[cur], c0);
}

__global__ void fc_kernel(const float* __restrict__ sums, const int* __restrict__ cnt,
                          const float* __restrict__ fcW, const float* __restrict__ fcb,
                          float* __restrict__ out) {
    int g = (blockIdx.x * blockDim.x + threadIdx.x) >> 6;
    int lane = threadIdx.x & 63;
    if (g >= NG) return;
    float c = fmaxf((float)cnt[g], 1.f);
    float val = (sums[g * 64 + lane] / c) * fcW[lane];
#pragma unroll
    for (int off = 32; off; off >>= 1) val += __shfl_down(val, off, 64);
    if (lane == 0) out[g] = 1.f / (1.f + expf(-(val + fcb[0])));
}

// ---------------------------------------------------------------------------
extern "C" void kernel_launch(void* const* d_in, const int* in_sizes, int n_in,
                              void* d_out, int out_size, void* d_ws, size_t ws_size,
                              hipStream_t stream) {
    const float* x   = (const float*)d_in[0];
    const int* ei    = (const int*)d_in[1];
    const int* batch = (const int*)d_in[2];
    const float* W[3], *attS[3], *attD[3], *bias[3], *gamma[3], *beta[3], *mean[3], *var[3];
    for (int l = 0; l < 3; ++l) {
        W[l]     = (const float*)d_in[3 + 8 * l + 0];
        attS[l]  = (const float*)d_in[3 + 8 * l + 1];
        attD[l]  = (const float*)d_in[3 + 8 * l + 2];
        bias[l]  = (const float*)d_in[3 + 8 * l + 3];
        gamma[l] = (const float*)d_in[3 + 8 * l + 4];
        beta[l]  = (const float*)d_in[3 + 8 * l + 5];
        mean[l]  = (const float*)d_in[3 + 8 * l + 6];
        var[l]   = (const float*)d_in[3 + 8 * l + 7];
    }
    const float* fcW = (const float*)d_in[27];
    const float* fcb = (const float*)d_in[28];
    float* out = (float*)d_out;               // [128] pooled sigmoid
    float* alpha_out = (float*)d_out + NG;    // [850000*4] layer-0 alpha

    // Workspace carve-up (256B aligned)
    char* p = (char*)d_ws;
    auto carve = [&](size_t bytes) {
        char* q = p;
        p += (bytes + 255) & ~(size_t)255;
        return q;
    };
    _Float16* Xh    = (_Float16*)carve(sizeof(_Float16) * NN * INDIM);
    _Float16* Wh    = (_Float16*)carve(sizeof(_Float16) * 16384);
    _Float16* Hh    = (_Float16*)carve(sizeof(_Float16) * NN * 64);  // gemm out
    _Float16* Hn    = (_Float16*)carve(sizeof(_Float16) * NN * 64);  // aggr out
    float* AS       = (float*)carve(sizeof(float) * NN * 4);
    float* AD       = (float*)carve(sizeof(float) * NN * 4);
    float* Z        = (float*)carve(sizeof(float) * NN * 4);
    int*   rowstart = (int*)carve(sizeof(int) * NN);
    int*   deg      = (int*)carve(sizeof(int) * NN);
    int*   rank     = (int*)carve(sizeof(int) * ETOT);
    int*   bsums    = (int*)carve(sizeof(int) * 64);
    int4*  csr      = (int4*)carve(sizeof(int4) * ETOT);
    float* psums    = (float*)carve(sizeof(float) * NG * 64);
    int*   pcnt     = (int*)carve(sizeof(int) * NG);

    // zero deg/psums/pcnt in one kernel (replaces 3 memsets)
    zero_kernel<<<(NN + NG * 64 + NG + 255) / 256, 256, 0, stream>>>(deg, psums, pcnt);

    // fp16 converts (X + all W, fused)
    cvt_kernel<<<(NX8 + 2048 + 255) / 256, 256, 0, stream>>>(x, W[0], W[1], W[2], Xh, Wh);

    // CSR build
    int nbScan = (NN + 1023) / 1024;
    degree_kernel<<<(ETOT + 255) / 256, 256, 0, stream>>>(ei, deg, rank);
    scan_block_kernel<<<nbScan, 1024, 0, stream>>>(deg, rowstart, bsums);
    scan_sums_kernel<<<1, 64, 0, stream>>>(bsums, nbScan);
    add_offsets_kernel<<<(NN + 255) / 256, 256, 0, stream>>>(rowstart, bsums);
    scatter_kernel<<<(ETOT + 255) / 256, 256, 0, stream>>>(ei, rowstart, rank, csr);

    int edgeBlocks = (NN * 64 + 255) / 256;
    int posBlocks = (ETOT + 255) / 256;
    int gemmBlocks = (NN + 63) / 64;   // 782

    // Layer 0 (K=128), writes Z then alpha
    gemm_att_kernel<128><<<gemmBlocks, 256, 0, stream>>>(Xh, Wh, attS[0], attD[0],
                                                         Hh, AS, AD);
    edge_aggr_kernel<true><<<edgeBlocks, 256, 0, stream>>>(
        Hh, AS, AD, rowstart, deg, csr,
        bias[0], gamma[0], beta[0], mean[0], var[0], Hn, Z);
    alpha_kernel<<<posBlocks, 256, 0, stream>>>(AS, AD, Z, csr, alpha_out);

    // Layer 1 (K=64)
    gemm_att_kernel<64><<<gemmBlocks, 256, 0, stream>>>(Hn, Wh + 8192, attS[1], attD[1],
                                                        Hh, AS, AD);
    edge_aggr_kernel<false><<<edgeBlocks, 256, 0, stream>>>(
        Hh, AS, AD, rowstart, deg, csr,
        bias[1], gamma[1], beta[1], mean[1], var[1], Hn, nullptr);

    // Layer 2 (K=64)
    gemm_att_kernel<64><<<gemmBlocks, 256, 0, stream>>>(Hn, Wh + 12288, attS[2], attD[2],
                                                        Hh, AS, AD);
    edge_aggr_kernel<false><<<edgeBlocks, 256, 0, stream>>>(
        Hh, AS, AD, rowstart, deg, csr,
        bias[2], gamma[2], beta[2], mean[2], var[2], Hn, nullptr);

    // Pool + FC
    int poolWaves = (NN + 63) / 64;
    pool_kernel<<<(poolWaves * 64 + 255) / 256, 256, 0, stream>>>(
        (const __half*)Hn, batch, psums, pcnt);
    fc_kernel<<<(NG * 64 + 255) / 256, 256, 0, stream>>>(psums, pcnt, fcW, fcb, out);
}

// Round 11
// 377.138 us; speedup vs baseline: 2.9465x; 1.0079x over previous
//
#include <hip/hip_runtime.h>
#include <hip/hip_fp16.h>
#include <math.h>

// Problem constants (match reference)
#define NN     50000
#define EE     800000
#define ETOT   (EE + NN)      // edges + self loops = 850000
#define INDIM  128
#define HEADS  4
#define NG     128
#define NEGS   0.2f
#define BNEPS  1e-5f

typedef _Float16 half8 __attribute__((ext_vector_type(8)));
typedef _Float16 half2v __attribute__((ext_vector_type(2)));
typedef float floatx4 __attribute__((ext_vector_type(4)));

// R11: csr carries ONLY src (alpha recomputed in original edge order needs no
// csr; dst is implicit in the row). Scatter store 16B->4B; aggr index reads
// 16->4 B/edge. alpha_kernel writes are now coalesced float4.

// ---------------------------------------------------------------------------
// CSR build. R6: rank captured in degree_kernel (already pays the random
// atomic); scatter is atomic-free.
__global__ void degree_kernel(const int* __restrict__ ei, int* __restrict__ deg,
                              int* __restrict__ rank) {
    int e = blockIdx.x * blockDim.x + threadIdx.x;
    if (e >= ETOT) return;
    int d = (e < EE) ? ei[EE + e] : (e - EE);
    rank[e] = atomicAdd(&deg[d], 1);
}

__global__ void scan_block_kernel(const int* __restrict__ deg, int* __restrict__ rowstart,
                                  int* __restrict__ bsums) {
    __shared__ int tmp[1024];
    int tid = threadIdx.x;
    int i = blockIdx.x * 1024 + tid;
    int v = (i < NN) ? deg[i] : 0;
    tmp[tid] = v;
    __syncthreads();
    for (int off = 1; off < 1024; off <<= 1) {
        int t = (tid >= off) ? tmp[tid - off] : 0;
        __syncthreads();
        tmp[tid] += t;
        __syncthreads();
    }
    if (i < NN) rowstart[i] = tmp[tid] - v;   // exclusive
    if (tid == 1023) bsums[blockIdx.x] = tmp[tid];
}

__global__ void scan_sums_kernel(int* __restrict__ bsums, int nb) {
    if (threadIdx.x == 0 && blockIdx.x == 0) {
        int acc = 0;
        for (int i = 0; i < nb; ++i) { int t = bsums[i]; bsums[i] = acc; acc += t; }
    }
}

__global__ void add_offsets_kernel(int* __restrict__ rowstart, const int* __restrict__ bsums) {
    int i = blockIdx.x * blockDim.x + threadIdx.x;
    if (i < NN) rowstart[i] += bsums[i >> 10];
}

// Atomic-free scatter, 4B payload (src only).
__global__ void scatter_kernel(const int* __restrict__ ei, const int* __restrict__ rowstart,
                               const int* __restrict__ rank, int* __restrict__ csr) {
    int e = blockIdx.x * blockDim.x + threadIdx.x;
    if (e >= ETOT) return;
    int s, d;
    if (e < EE) { s = ei[e]; d = ei[EE + e]; }
    else        { s = e - EE; d = e - EE; }
    int pos = rowstart[d] + rank[e];
    csr[pos] = s;
}

// ---------------------------------------------------------------------------
// Fused prep: fp32->fp16 converts (X, all W) + zero-init deg/psums/pcnt.
#define NX8 (NN * INDIM / 8)
#define PREP_TOT (NX8 + 2048 + NN + NG * 64 + NG)
__global__ __launch_bounds__(256) void prep_kernel(const float* __restrict__ x,
                                                   const float* __restrict__ W0,
                                                   const float* __restrict__ W1,
                                                   const float* __restrict__ W2,
                                                   _Float16* __restrict__ Xh,
                                                   _Float16* __restrict__ Wh,
                                                   int* __restrict__ deg,
                                                   float* __restrict__ psums,
                                                   int* __restrict__ pcnt) {
    int i = blockIdx.x * blockDim.x + threadIdx.x;     // x8 floats
    if (i < NX8) {
        float4 v0 = *(const float4*)(x + (size_t)i * 8);
        float4 v1 = *(const float4*)(x + (size_t)i * 8 + 4);
        half8 o;
        o[0] = (_Float16)v0.x; o[1] = (_Float16)v0.y;
        o[2] = (_Float16)v0.z; o[3] = (_Float16)v0.w;
        o[4] = (_Float16)v1.x; o[5] = (_Float16)v1.y;
        o[6] = (_Float16)v1.z; o[7] = (_Float16)v1.w;
        *(half8*)(Xh + (size_t)i * 8) = o;
    } else if (i < NX8 + 2048) {
        int wi = (i - NX8) * 8;            // 8-groups never straddle W arrays
#pragma unroll
        for (int j = 0; j < 8; ++j) {
            int idx = wi + j;
            float v = (idx < 8192) ? W0[idx]
                    : ((idx < 12288) ? W1[idx - 8192] : W2[idx - 12288]);
            Wh[idx] = (_Float16)v;
        }
    } else if (i < NX8 + 2048 + NN) {
        deg[i - NX8 - 2048] = 0;
    } else if (i < NX8 + 2048 + NN + NG * 64) {
        psums[i - NX8 - 2048 - NN] = 0.f;
    } else if (i < PREP_TOT) {
        pcnt[i - NX8 - 2048 - NN - NG * 64] = 0;
    }
}

// ---------------------------------------------------------------------------
// MFMA GEMM (h = x @ W^T) + attention dots. Block = 4 waves; each wave owns
// 16 nodes x 64 cols = 4 col-tiles of 16x16, K in 32-chunks.
// A frag: X[wbase + (lane&15)][kb*32 + quad*8 ..+8]; B frag same shape on W.
// C/D: node = wbase + quad*4 + reg, col = t*16 + (lane&15).
template <int DD>
__global__ __launch_bounds__(256) void gemm_att_kernel(
    const _Float16* __restrict__ X, const _Float16* __restrict__ Wh,
    const float* __restrict__ attS, const float* __restrict__ attD,
    _Float16* __restrict__ H, float* __restrict__ AS, float* __restrict__ AD) {
    constexpr int KB = DD / 32;
    int tid = threadIdx.x;
    int wv = tid >> 6;
    int lane = tid & 63;
    int quad = lane >> 4;
    int n = lane & 15;
    int wbase = blockIdx.x * 64 + wv * 16;

    int arow = wbase + n;
    if (arow >= NN) arow = NN - 1;          // clamp (stores are guarded)
    half8 a[KB];
#pragma unroll
    for (int kb = 0; kb < KB; ++kb)
        a[kb] = *(const half8*)(X + (size_t)arow * DD + kb * 32 + quad * 8);

    floatx4 c[4];
#pragma unroll
    for (int t = 0; t < 4; ++t) {
        floatx4 acc = {0.f, 0.f, 0.f, 0.f};
#pragma unroll
        for (int kb = 0; kb < KB; ++kb) {
            half8 b = *(const half8*)(Wh + (size_t)(t * 16 + n) * DD + kb * 32 + quad * 8);
            acc = __builtin_amdgcn_mfma_f32_16x16x32_f16(a[kb], b, acc, 0, 0, 0);
        }
        c[t] = acc;
    }

    float as_l[4], ad_l[4];
#pragma unroll
    for (int t = 0; t < 4; ++t) {
        as_l[t] = attS[t * 16 + n];
        ad_l[t] = attD[t * 16 + n];
    }
#pragma unroll
    for (int r = 0; r < 4; ++r) {
        int node = wbase + quad * 4 + r;
        bool ok = node < NN;
#pragma unroll
        for (int t = 0; t < 4; ++t) {
            float h = c[t][r];
            if (ok) H[(size_t)node * 64 + t * 16 + n] = (_Float16)h;
            float vs = h * as_l[t];
            float vd = h * ad_l[t];
#pragma unroll
            for (int off = 8; off; off >>= 1) {
                vs += __shfl_down(vs, off, 16);
                vd += __shfl_down(vd, off, 16);
            }
            if (ok && n == 0) {
                AS[node * 4 + t] = vs;
                AD[node * 4 + t] = vd;
            }
        }
    }
}

// ---------------------------------------------------------------------------
// Per-node aggregation, half-wave edge pairing (R10): half 0 serves edges
// k..k+3, half 1 serves k+4..k+7 (consecutive 4B src reads pack cache lines).
// Each lane covers 2 channels via fp16x2 gathers. Cross-half combine:
// shfl_xor(32). Inline attention weights (R7); no max-subtraction.
template <bool WRITE_Z>
__global__ __launch_bounds__(256) void edge_aggr_kernel(
    const _Float16* __restrict__ H, const float* __restrict__ AS,
    const float* __restrict__ AD,
    const int* __restrict__ rowstart, const int* __restrict__ deg,
    const int* __restrict__ csr,
    const float* __restrict__ bias, const float* __restrict__ gamma,
    const float* __restrict__ beta, const float* __restrict__ mean,
    const float* __restrict__ var, _Float16* __restrict__ Hout,
    float* __restrict__ Z) {
    int v = (blockIdx.x * blockDim.x + threadIdx.x) >> 6;
    if (v >= NN) return;
    int lane = threadIdx.x & 63;
    int half = lane >> 5;
    int l32 = lane & 31;
    int head = l32 >> 3;
    int ch2 = l32 * 2;
    float adv = AD[v * 4 + head];
    int start = rowstart[v];
    int cnt = deg[v];                    // >= 1 (self loop)
    const int* srow = csr + start;
    float z = 0.f, acc0 = 0.f, acc1 = 0.f;
    int k = 0;
    for (; k + 8 <= cnt; k += 8) {
        int b = k + half * 4;
        int s0 = srow[b + 0];
        int s1 = srow[b + 1];
        int s2 = srow[b + 2];
        int s3 = srow[b + 3];
        float a0 = AS[(size_t)s0 * 4 + head];
        float a1 = AS[(size_t)s1 * 4 + head];
        float a2 = AS[(size_t)s2 * 4 + head];
        float a3 = AS[(size_t)s3 * 4 + head];
        half2v h0 = *(const half2v*)(H + (size_t)s0 * 64 + ch2);
        half2v h1 = *(const half2v*)(H + (size_t)s1 * 64 + ch2);
        half2v h2 = *(const half2v*)(H + (size_t)s2 * 64 + ch2);
        half2v h3 = *(const half2v*)(H + (size_t)s3 * 64 + ch2);
        float l0 = a0 + adv; l0 = l0 > 0.f ? l0 : NEGS * l0; float p0 = __expf(l0);
        float l1 = a1 + adv; l1 = l1 > 0.f ? l1 : NEGS * l1; float p1 = __expf(l1);
        float l2 = a2 + adv; l2 = l2 > 0.f ? l2 : NEGS * l2; float p2 = __expf(l2);
        float l3 = a3 + adv; l3 = l3 > 0.f ? l3 : NEGS * l3; float p3 = __expf(l3);
        z += (p0 + p1) + (p2 + p3);
        acc0 = fmaf(p0, (float)h0[0], acc0); acc1 = fmaf(p0, (float)h0[1], acc1);
        acc0 = fmaf(p1, (float)h1[0], acc0); acc1 = fmaf(p1, (float)h1[1], acc1);
        acc0 = fmaf(p2, (float)h2[0], acc0); acc1 = fmaf(p2, (float)h2[1], acc1);
        acc0 = fmaf(p3, (float)h3[0], acc0); acc1 = fmaf(p3, (float)h3[1], acc1);
    }
    for (; k < cnt; k += 2) {
        int idx = k + half;
        if (idx < cnt) {
            int s = srow[idx];
            float a = AS[(size_t)s * 4 + head];
            half2v hv = *(const half2v*)(H + (size_t)s * 64 + ch2);
            float l = a + adv; l = l > 0.f ? l : NEGS * l;
            float p = __expf(l);
            z += p;
            acc0 = fmaf(p, (float)hv[0], acc0);
            acc1 = fmaf(p, (float)hv[1], acc1);
        }
    }
    // combine the two half-wave partial sums
    z    += __shfl_xor(z, 32);
    acc0 += __shfl_xor(acc0, 32);
    acc1 += __shfl_xor(acc1, 32);
    if (half == 0) {
        if (WRITE_Z && (l32 & 7) == 0) Z[v * 4 + head] = z;
        float2 bi = *(const float2*)(bias + ch2);
        float2 ga = *(const float2*)(gamma + ch2);
        float2 be = *(const float2*)(beta + ch2);
        float2 mu = *(const float2*)(mean + ch2);
        float2 va = *(const float2*)(var + ch2);
        float r0 = fmaxf(acc0 / z + bi.x, 0.f);
        float r1 = fmaxf(acc1 / z + bi.y, 0.f);
        r0 = ga.x * (r0 - mu.x) * rsqrtf(va.x + BNEPS) + be.x;
        r1 = ga.y * (r1 - mu.y) * rsqrtf(va.y + BNEPS) + be.y;
        half2v o;
        o[0] = (_Float16)r0;
        o[1] = (_Float16)r1;
        *(half2v*)(Hout + (size_t)v * 64 + ch2) = o;
    }
}

// ---------------------------------------------------------------------------
// Layer-0 alpha, ORIGINAL edge order (R11): needs no csr; recomputes p from
// AS/AD (identical formula+inputs as aggr => identical values), divides by Z,
// writes coalesced float4 at alpha_out + e*4.
__global__ __launch_bounds__(256) void alpha_kernel(
    const int* __restrict__ ei,
    const float* __restrict__ AS, const float* __restrict__ AD,
    const float* __restrict__ Z, float* __restrict__ alpha_out) {
    int e = blockIdx.x * blockDim.x + threadIdx.x;
    if (e >= ETOT) return;
    int s, d;
    if (e < EE) { s = ei[e]; d = ei[EE + e]; }
    else        { s = e - EE; d = e - EE; }
    float4 as = *(const float4*)(AS + (size_t)s * 4);
    float4 ad = *(const float4*)(AD + (size_t)d * 4);
    float4 z4 = *(const float4*)(Z + (size_t)d * 4);
    float l;
    float4 a;
    l = as.x + ad.x; l = l > 0.f ? l : NEGS * l; a.x = __expf(l) / z4.x;
    l = as.y + ad.y; l = l > 0.f ? l : NEGS * l; a.y = __expf(l) / z4.y;
    l = as.z + ad.z; l = l > 0.f ? l : NEGS * l; a.z = __expf(l) / z4.z;
    l = as.w + ad.w; l = l > 0.f ? l : NEGS * l; a.w = __expf(l) / z4.w;
    *(float4*)(alpha_out + (size_t)e * 4) = a;
}

// ---------------------------------------------------------------------------
// Mean pool over sorted batch ids (fp16 input): one wave per 64-node chunk,
// local accumulation, atomic flush on graph-id change.
__global__ __launch_bounds__(256) void pool_kernel(const __half* __restrict__ H,
                                                   const int* __restrict__ batch,
                                                   float* __restrict__ sums,
                                                   int* __restrict__ cnt) {
    int wid = (blockIdx.x * blockDim.x + threadIdx.x) >> 6;
    int lane = threadIdx.x & 63;
    int base = wid * 64;
    if (base >= NN) return;
    int end = min(base + 64, NN);
    int cur = batch[base];
    float acc = 0.f;
    int c0 = 0;
    for (int i = base; i < end; ++i) {
        int g = batch[i];
        if (g != cur) {
            atomicAdd(&sums[cur * 64 + lane], acc);
            if (lane == 0) atomicAdd(&cnt[cur], c0);
            cur = g; acc = 0.f; c0 = 0;
        }
        acc += __half2float(H[(size_t)i * 64 + lane]);
        c0++;
    }
    atomicAdd(&sums[cur * 64 + lane], acc);
    if (lane == 0) atomicAdd(&cnt[cur], c0);
}

__global__ void fc_kernel(const float* __restrict__ sums, const int* __restrict__ cnt,
                          const float* __restrict__ fcW, const float* __restrict__ fcb,
                          float* __restrict__ out) {
    int g = (blockIdx.x * blockDim.x + threadIdx.x) >> 6;
    int lane = threadIdx.x & 63;
    if (g >= NG) return;
    float c = fmaxf((float)cnt[g], 1.f);
    float val = (sums[g * 64 + lane] / c) * fcW[lane];
#pragma unroll
    for (int off = 32; off; off >>= 1) val += __shfl_down(val, off, 64);
    if (lane == 0) out[g] = 1.f / (1.f + expf(-(val + fcb[0])));
}

// ---------------------------------------------------------------------------
extern "C" void kernel_launch(void* const* d_in, const int* in_sizes, int n_in,
                              void* d_out, int out_size, void* d_ws, size_t ws_size,
                              hipStream_t stream) {
    const float* x   = (const float*)d_in[0];
    const int* ei    = (const int*)d_in[1];
    const int* batch = (const int*)d_in[2];
    const float* W[3], *attS[3], *attD[3], *bias[3], *gamma[3], *beta[3], *mean[3], *var[3];
    for (int l = 0; l < 3; ++l) {
        W[l]     = (const float*)d_in[3 + 8 * l + 0];
        attS[l]  = (const float*)d_in[3 + 8 * l + 1];
        attD[l]  = (const float*)d_in[3 + 8 * l + 2];
        bias[l]  = (const float*)d_in[3 + 8 * l + 3];
        gamma[l] = (const float*)d_in[3 + 8 * l + 4];
        beta[l]  = (const float*)d_in[3 + 8 * l + 5];
        mean[l]  = (const float*)d_in[3 + 8 * l + 6];
        var[l]   = (const float*)d_in[3 + 8 * l + 7];
    }
    const float* fcW = (const float*)d_in[27];
    const float* fcb = (const float*)d_in[28];
    float* out = (float*)d_out;               // [128] pooled sigmoid
    float* alpha_out = (float*)d_out + NG;    // [850000*4] layer-0 alpha

    // Workspace carve-up (256B aligned)
    char* p = (char*)d_ws;
    auto carve = [&](size_t bytes) {
        char* q = p;
        p += (bytes + 255) & ~(size_t)255;
        return q;
    };
    _Float16* Xh    = (_Float16*)carve(sizeof(_Float16) * NN * INDIM);
    _Float16* Wh    = (_Float16*)carve(sizeof(_Float16) * 16384);
    _Float16* Hh    = (_Float16*)carve(sizeof(_Float16) * NN * 64);  // gemm out
    _Float16* Hn    = (_Float16*)carve(sizeof(_Float16) * NN * 64);  // aggr out
    float* AS       = (float*)carve(sizeof(float) * NN * 4);
    float* AD       = (float*)carve(sizeof(float) * NN * 4);
    float* Z        = (float*)carve(sizeof(float) * NN * 4);
    int*   rowstart = (int*)carve(sizeof(int) * NN);
    int*   deg      = (int*)carve(sizeof(int) * NN);
    int*   rank     = (int*)carve(sizeof(int) * ETOT);
    int*   bsums    = (int*)carve(sizeof(int) * 64);
    int*   csr      = (int*)carve(sizeof(int) * ETOT);
    float* psums    = (float*)carve(sizeof(float) * NG * 64);
    int*   pcnt     = (int*)carve(sizeof(int) * NG);

    // fp16 converts + zero-init, one launch
    prep_kernel<<<(PREP_TOT + 255) / 256, 256, 0, stream>>>(
        x, W[0], W[1], W[2], Xh, Wh, deg, psums, pcnt);

    // CSR build
    int nbScan = (NN + 1023) / 1024;
    degree_kernel<<<(ETOT + 255) / 256, 256, 0, stream>>>(ei, deg, rank);
    scan_block_kernel<<<nbScan, 1024, 0, stream>>>(deg, rowstart, bsums);
    scan_sums_kernel<<<1, 64, 0, stream>>>(bsums, nbScan);
    add_offsets_kernel<<<(NN + 255) / 256, 256, 0, stream>>>(rowstart, bsums);
    scatter_kernel<<<(ETOT + 255) / 256, 256, 0, stream>>>(ei, rowstart, rank, csr);

    int edgeBlocks = (NN * 64 + 255) / 256;
    int posBlocks = (ETOT + 255) / 256;
    int gemmBlocks = (NN + 63) / 64;   // 782

    // Layer 0 (K=128), writes Z then alpha
    gemm_att_kernel<128><<<gemmBlocks, 256, 0, stream>>>(Xh, Wh, attS[0], attD[0],
                                                         Hh, AS, AD);
    edge_aggr_kernel<true><<<edgeBlocks, 256, 0, stream>>>(
        Hh, AS, AD, rowstart, deg, csr,
        bias[0], gamma[0], beta[0], mean[0], var[0], Hn, Z);
    alpha_kernel<<<posBlocks, 256, 0, stream>>>(ei, AS, AD, Z, alpha_out);

    // Layer 1 (K=64)
    gemm_att_kernel<64><<<gemmBlocks, 256, 0, stream>>>(Hn, Wh + 8192, attS[1], attD[1],
                                                        Hh, AS, AD);
    edge_aggr_kernel<false><<<edgeBlocks, 256, 0, stream>>>(
        Hh, AS, AD, rowstart, deg, csr,
        bias[1], gamma[1], beta[1], mean[1], var[1], Hn, nullptr);

    // Layer 2 (K=64)
    gemm_att_kernel<64><<<gemmBlocks, 256, 0, stream>>>(Hn, Wh + 12288, attS[2], attD[2],
                                                        Hh, AS, AD);
    edge_aggr_kernel<false><<<edgeBlocks, 256, 0, stream>>>(
        Hh, AS, AD, rowstart, deg, csr,
        bias[2], gamma[2], beta[2], mean[2], var[2], Hn, nullptr);

    // Pool + FC
    int poolWaves = (NN + 63) / 64;
    pool_kernel<<<(poolWaves * 64 + 255) / 256, 256, 0, stream>>>(
        (const __half*)Hn, batch, psums, pcnt);
    fc_kernel<<<(NG * 64 + 255) / 256, 256, 0, stream>>>(psums, pcnt, fcW, fcb, out);
}

// Round 12
// 365.593 us; speedup vs baseline: 3.0395x; 1.0316x over previous
//
#include <hip/hip_runtime.h>
#include <hip/hip_fp16.h>
#include <math.h>

// Problem constants (match reference)
#define NN     50000
#define EE     800000
#define ETOT   (EE + NN)      // edges + self loops = 850000
#define INDIM  128
#define HEADS  4
#define NG     128
#define NEGS   0.2f
#define BNEPS  1e-5f

typedef _Float16 half8 __attribute__((ext_vector_type(8)));
typedef _Float16 half4v __attribute__((ext_vector_type(4)));
typedef _Float16 half2v __attribute__((ext_vector_type(2)));
typedef float floatx4 __attribute__((ext_vector_type(4)));

// R12: edge_aggr quarter-wave edge parallelism — each 16-lane quarter serves
// its own edge, lanes cover 4 channels via fp16x4 (8B) gathers. 16 edges in
// flight per wave; serial loop = cnt/4. Combine: shfl_xor(16)+shfl_xor(32).

// ---------------------------------------------------------------------------
// CSR build. R6: rank captured in degree_kernel (already pays the random
// atomic); scatter is atomic-free. R11: csr = src only (4B scatter payload).
__global__ void degree_kernel(const int* __restrict__ ei, int* __restrict__ deg,
                              int* __restrict__ rank) {
    int e = blockIdx.x * blockDim.x + threadIdx.x;
    if (e >= ETOT) return;
    int d = (e < EE) ? ei[EE + e] : (e - EE);
    rank[e] = atomicAdd(&deg[d], 1);
}

__global__ void scan_block_kernel(const int* __restrict__ deg, int* __restrict__ rowstart,
                                  int* __restrict__ bsums) {
    __shared__ int tmp[1024];
    int tid = threadIdx.x;
    int i = blockIdx.x * 1024 + tid;
    int v = (i < NN) ? deg[i] : 0;
    tmp[tid] = v;
    __syncthreads();
    for (int off = 1; off < 1024; off <<= 1) {
        int t = (tid >= off) ? tmp[tid - off] : 0;
        __syncthreads();
        tmp[tid] += t;
        __syncthreads();
    }
    if (i < NN) rowstart[i] = tmp[tid] - v;   // exclusive
    if (tid == 1023) bsums[blockIdx.x] = tmp[tid];
}

__global__ void scan_sums_kernel(int* __restrict__ bsums, int nb) {
    if (threadIdx.x == 0 && blockIdx.x == 0) {
        int acc = 0;
        for (int i = 0; i < nb; ++i) { int t = bsums[i]; bsums[i] = acc; acc += t; }
    }
}

__global__ void add_offsets_kernel(int* __restrict__ rowstart, const int* __restrict__ bsums) {
    int i = blockIdx.x * blockDim.x + threadIdx.x;
    if (i < NN) rowstart[i] += bsums[i >> 10];
}

// Atomic-free scatter, 4B payload (src only).
__global__ void scatter_kernel(const int* __restrict__ ei, const int* __restrict__ rowstart,
                               const int* __restrict__ rank, int* __restrict__ csr) {
    int e = blockIdx.x * blockDim.x + threadIdx.x;
    if (e >= ETOT) return;
    int s, d;
    if (e < EE) { s = ei[e]; d = ei[EE + e]; }
    else        { s = e - EE; d = e - EE; }
    int pos = rowstart[d] + rank[e];
    csr[pos] = s;
}

// ---------------------------------------------------------------------------
// Fused prep: fp32->fp16 converts (X, all W) + zero-init deg/psums/pcnt.
#define NX8 (NN * INDIM / 8)
#define PREP_TOT (NX8 + 2048 + NN + NG * 64 + NG)
__global__ __launch_bounds__(256) void prep_kernel(const float* __restrict__ x,
                                                   const float* __restrict__ W0,
                                                   const float* __restrict__ W1,
                                                   const float* __restrict__ W2,
                                                   _Float16* __restrict__ Xh,
                                                   _Float16* __restrict__ Wh,
                                                   int* __restrict__ deg,
                                                   float* __restrict__ psums,
                                                   int* __restrict__ pcnt) {
    int i = blockIdx.x * blockDim.x + threadIdx.x;     // x8 floats
    if (i < NX8) {
        float4 v0 = *(const float4*)(x + (size_t)i * 8);
        float4 v1 = *(const float4*)(x + (size_t)i * 8 + 4);
        half8 o;
        o[0] = (_Float16)v0.x; o[1] = (_Float16)v0.y;
        o[2] = (_Float16)v0.z; o[3] = (_Float16)v0.w;
        o[4] = (_Float16)v1.x; o[5] = (_Float16)v1.y;
        o[6] = (_Float16)v1.z; o[7] = (_Float16)v1.w;
        *(half8*)(Xh + (size_t)i * 8) = o;
    } else if (i < NX8 + 2048) {
        int wi = (i - NX8) * 8;            // 8-groups never straddle W arrays
#pragma unroll
        for (int j = 0; j < 8; ++j) {
            int idx = wi + j;
            float v = (idx < 8192) ? W0[idx]
                    : ((idx < 12288) ? W1[idx - 8192] : W2[idx - 12288]);
            Wh[idx] = (_Float16)v;
        }
    } else if (i < NX8 + 2048 + NN) {
        deg[i - NX8 - 2048] = 0;
    } else if (i < NX8 + 2048 + NN + NG * 64) {
        psums[i - NX8 - 2048 - NN] = 0.f;
    } else if (i < PREP_TOT) {
        pcnt[i - NX8 - 2048 - NN - NG * 64] = 0;
    }
}

// ---------------------------------------------------------------------------
// MFMA GEMM (h = x @ W^T) + attention dots. Block = 4 waves; each wave owns
// 16 nodes x 64 cols = 4 col-tiles of 16x16, K in 32-chunks.
// A frag: X[wbase + (lane&15)][kb*32 + quad*8 ..+8]; B frag same shape on W.
// C/D: node = wbase + quad*4 + reg, col = t*16 + (lane&15).
template <int DD>
__global__ __launch_bounds__(256) void gemm_att_kernel(
    const _Float16* __restrict__ X, const _Float16* __restrict__ Wh,
    const float* __restrict__ attS, const float* __restrict__ attD,
    _Float16* __restrict__ H, float* __restrict__ AS, float* __restrict__ AD) {
    constexpr int KB = DD / 32;
    int tid = threadIdx.x;
    int wv = tid >> 6;
    int lane = tid & 63;
    int quad = lane >> 4;
    int n = lane & 15;
    int wbase = blockIdx.x * 64 + wv * 16;

    int arow = wbase + n;
    if (arow >= NN) arow = NN - 1;          // clamp (stores are guarded)
    half8 a[KB];
#pragma unroll
    for (int kb = 0; kb < KB; ++kb)
        a[kb] = *(const half8*)(X + (size_t)arow * DD + kb * 32 + quad * 8);

    floatx4 c[4];
#pragma unroll
    for (int t = 0; t < 4; ++t) {
        floatx4 acc = {0.f, 0.f, 0.f, 0.f};
#pragma unroll
        for (int kb = 0; kb < KB; ++kb) {
            half8 b = *(const half8*)(Wh + (size_t)(t * 16 + n) * DD + kb * 32 + quad * 8);
            acc = __builtin_amdgcn_mfma_f32_16x16x32_f16(a[kb], b, acc, 0, 0, 0);
        }
        c[t] = acc;
    }

    float as_l[4], ad_l[4];
#pragma unroll
    for (int t = 0; t < 4; ++t) {
        as_l[t] = attS[t * 16 + n];
        ad_l[t] = attD[t * 16 + n];
    }
#pragma unroll
    for (int r = 0; r < 4; ++r) {
        int node = wbase + quad * 4 + r;
        bool ok = node < NN;
#pragma unroll
        for (int t = 0; t < 4; ++t) {
            float h = c[t][r];
            if (ok) H[(size_t)node * 64 + t * 16 + n] = (_Float16)h;
            float vs = h * as_l[t];
            float vd = h * ad_l[t];
#pragma unroll
            for (int off = 8; off; off >>= 1) {
                vs += __shfl_down(vs, off, 16);
                vd += __shfl_down(vd, off, 16);
            }
            if (ok && n == 0) {
                AS[node * 4 + t] = vs;
                AD[node * 4 + t] = vd;
            }
        }
    }
}

// ---------------------------------------------------------------------------
// Per-node aggregation, quarter-wave edge parallelism (R12).
// quarter q = lane>>4 serves edges k+q*4..k+q*4+3 per 16-edge iteration; each
// lane covers 4 channels (ch4 = (lane&15)*4, head = (lane&15)>>2) via fp16x4
// gathers (16 lanes x 8B = full 128B row per quarter). Cross-quarter combine:
// shfl_xor(16) + shfl_xor(32). Inline attention weights (R7); no
// max-subtraction (logits O(1), exp cannot overflow).
template <bool WRITE_Z>
__global__ __launch_bounds__(256) void edge_aggr_kernel(
    const _Float16* __restrict__ H, const float* __restrict__ AS,
    const float* __restrict__ AD,
    const int* __restrict__ rowstart, const int* __restrict__ deg,
    const int* __restrict__ csr,
    const float* __restrict__ bias, const float* __restrict__ gamma,
    const float* __restrict__ beta, const float* __restrict__ mean,
    const float* __restrict__ var, _Float16* __restrict__ Hout,
    float* __restrict__ Z) {
    int v = (blockIdx.x * blockDim.x + threadIdx.x) >> 6;
    if (v >= NN) return;
    int lane = threadIdx.x & 63;
    int q = lane >> 4;
    int l16 = lane & 15;
    int head = l16 >> 2;
    int ch4 = l16 * 4;
    float adv = AD[v * 4 + head];
    int start = rowstart[v];
    int cnt = deg[v];                    // >= 1 (self loop)
    const int* srow = csr + start;
    float z = 0.f;
    float acc0 = 0.f, acc1 = 0.f, acc2 = 0.f, acc3 = 0.f;
    int k = 0;
    for (; k + 16 <= cnt; k += 16) {
        int b = k + q * 4;
        int s0 = srow[b + 0];
        int s1 = srow[b + 1];
        int s2 = srow[b + 2];
        int s3 = srow[b + 3];
        float a0 = AS[(size_t)s0 * 4 + head];
        float a1 = AS[(size_t)s1 * 4 + head];
        float a2 = AS[(size_t)s2 * 4 + head];
        float a3 = AS[(size_t)s3 * 4 + head];
        half4v h0 = *(const half4v*)(H + (size_t)s0 * 64 + ch4);
        half4v h1 = *(const half4v*)(H + (size_t)s1 * 64 + ch4);
        half4v h2 = *(const half4v*)(H + (size_t)s2 * 64 + ch4);
        half4v h3 = *(const half4v*)(H + (size_t)s3 * 64 + ch4);
        float l0 = a0 + adv; l0 = l0 > 0.f ? l0 : NEGS * l0; float p0 = __expf(l0);
        float l1 = a1 + adv; l1 = l1 > 0.f ? l1 : NEGS * l1; float p1 = __expf(l1);
        float l2 = a2 + adv; l2 = l2 > 0.f ? l2 : NEGS * l2; float p2 = __expf(l2);
        float l3 = a3 + adv; l3 = l3 > 0.f ? l3 : NEGS * l3; float p3 = __expf(l3);
        z += (p0 + p1) + (p2 + p3);
        acc0 = fmaf(p0, (float)h0[0], acc0); acc1 = fmaf(p0, (float)h0[1], acc1);
        acc2 = fmaf(p0, (float)h0[2], acc2); acc3 = fmaf(p0, (float)h0[3], acc3);
        acc0 = fmaf(p1, (float)h1[0], acc0); acc1 = fmaf(p1, (float)h1[1], acc1);
        acc2 = fmaf(p1, (float)h1[2], acc2); acc3 = fmaf(p1, (float)h1[3], acc3);
        acc0 = fmaf(p2, (float)h2[0], acc0); acc1 = fmaf(p2, (float)h2[1], acc1);
        acc2 = fmaf(p2, (float)h2[2], acc2); acc3 = fmaf(p2, (float)h2[3], acc3);
        acc0 = fmaf(p3, (float)h3[0], acc0); acc1 = fmaf(p3, (float)h3[1], acc1);
        acc2 = fmaf(p3, (float)h3[2], acc2); acc3 = fmaf(p3, (float)h3[3], acc3);
    }
    for (; k < cnt; k += 4) {
        int idx = k + q;
        if (idx < cnt) {
            int s = srow[idx];
            float a = AS[(size_t)s * 4 + head];
            half4v hv = *(const half4v*)(H + (size_t)s * 64 + ch4);
            float l = a + adv; l = l > 0.f ? l : NEGS * l;
            float p = __expf(l);
            z += p;
            acc0 = fmaf(p, (float)hv[0], acc0);
            acc1 = fmaf(p, (float)hv[1], acc1);
            acc2 = fmaf(p, (float)hv[2], acc2);
            acc3 = fmaf(p, (float)hv[3], acc3);
        }
    }
    // combine the four quarter-wave partial sums
    z    += __shfl_xor(z, 16);    z    += __shfl_xor(z, 32);
    acc0 += __shfl_xor(acc0, 16); acc0 += __shfl_xor(acc0, 32);
    acc1 += __shfl_xor(acc1, 16); acc1 += __shfl_xor(acc1, 32);
    acc2 += __shfl_xor(acc2, 16); acc2 += __shfl_xor(acc2, 32);
    acc3 += __shfl_xor(acc3, 16); acc3 += __shfl_xor(acc3, 32);
    if (q == 0) {
        if (WRITE_Z && (l16 & 3) == 0) Z[v * 4 + head] = z;
        float4 bi = *(const float4*)(bias + ch4);
        float4 ga = *(const float4*)(gamma + ch4);
        float4 be = *(const float4*)(beta + ch4);
        float4 mu = *(const float4*)(mean + ch4);
        float4 va = *(const float4*)(var + ch4);
        float r0 = fmaxf(acc0 / z + bi.x, 0.f);
        float r1 = fmaxf(acc1 / z + bi.y, 0.f);
        float r2 = fmaxf(acc2 / z + bi.z, 0.f);
        float r3 = fmaxf(acc3 / z + bi.w, 0.f);
        r0 = ga.x * (r0 - mu.x) * rsqrtf(va.x + BNEPS) + be.x;
        r1 = ga.y * (r1 - mu.y) * rsqrtf(va.y + BNEPS) + be.y;
        r2 = ga.z * (r2 - mu.z) * rsqrtf(va.z + BNEPS) + be.z;
        r3 = ga.w * (r3 - mu.w) * rsqrtf(va.w + BNEPS) + be.w;
        half4v o;
        o[0] = (_Float16)r0;
        o[1] = (_Float16)r1;
        o[2] = (_Float16)r2;
        o[3] = (_Float16)r3;
        *(half4v*)(Hout + (size_t)v * 64 + ch4) = o;
    }
}

// ---------------------------------------------------------------------------
// Layer-0 alpha, ORIGINAL edge order (R11): needs no csr; recomputes p from
// AS/AD (identical formula+inputs as aggr => identical values), divides by Z,
// writes coalesced float4 at alpha_out + e*4.
__global__ __launch_bounds__(256) void alpha_kernel(
    const int* __restrict__ ei,
    const float* __restrict__ AS, const float* __restrict__ AD,
    const float* __restrict__ Z, float* __restrict__ alpha_out) {
    int e = blockIdx.x * blockDim.x + threadIdx.x;
    if (e >= ETOT) return;
    int s, d;
    if (e < EE) { s = ei[e]; d = ei[EE + e]; }
    else        { s = e - EE; d = e - EE; }
    float4 as = *(const float4*)(AS + (size_t)s * 4);
    float4 ad = *(const float4*)(AD + (size_t)d * 4);
    float4 z4 = *(const float4*)(Z + (size_t)d * 4);
    float l;
    float4 a;
    l = as.x + ad.x; l = l > 0.f ? l : NEGS * l; a.x = __expf(l) / z4.x;
    l = as.y + ad.y; l = l > 0.f ? l : NEGS * l; a.y = __expf(l) / z4.y;
    l = as.z + ad.z; l = l > 0.f ? l : NEGS * l; a.z = __expf(l) / z4.z;
    l = as.w + ad.w; l = l > 0.f ? l : NEGS * l; a.w = __expf(l) / z4.w;
    *(float4*)(alpha_out + (size_t)e * 4) = a;
}

// ---------------------------------------------------------------------------
// Mean pool over sorted batch ids (fp16 input): one wave per 64-node chunk,
// local accumulation, atomic flush on graph-id change.
__global__ __launch_bounds__(256) void pool_kernel(const __half* __restrict__ H,
                                                   const int* __restrict__ batch,
                                                   float* __restrict__ sums,
                                                   int* __restrict__ cnt) {
    int wid = (blockIdx.x * blockDim.x + threadIdx.x) >> 6;
    int lane = threadIdx.x & 63;
    int base = wid * 64;
    if (base >= NN) return;
    int end = min(base + 64, NN);
    int cur = batch[base];
    float acc = 0.f;
    int c0 = 0;
    for (int i = base; i < end; ++i) {
        int g = batch[i];
        if (g != cur) {
            atomicAdd(&sums[cur * 64 + lane], acc);
            if (lane == 0) atomicAdd(&cnt[cur], c0);
            cur = g; acc = 0.f; c0 = 0;
        }
        acc += __half2float(H[(size_t)i * 64 + lane]);
        c0++;
    }
    atomicAdd(&sums[cur * 64 + lane], acc);
    if (lane == 0) atomicAdd(&cnt[cur], c0);
}

__global__ void fc_kernel(const float* __restrict__ sums, const int* __restrict__ cnt,
                          const float* __restrict__ fcW, const float* __restrict__ fcb,
                          float* __restrict__ out) {
    int g = (blockIdx.x * blockDim.x + threadIdx.x) >> 6;
    int lane = threadIdx.x & 63;
    if (g >= NG) return;
    float c = fmaxf((float)cnt[g], 1.f);
    float val = (sums[g * 64 + lane] / c) * fcW[lane];
#pragma unroll
    for (int off = 32; off; off >>= 1) val += __shfl_down(val, off, 64);
    if (lane == 0) out[g] = 1.f / (1.f + expf(-(val + fcb[0])));
}

// ---------------------------------------------------------------------------
extern "C" void kernel_launch(void* const* d_in, const int* in_sizes, int n_in,
                              void* d_out, int out_size, void* d_ws, size_t ws_size,
                              hipStream_t stream) {
    const float* x   = (const float*)d_in[0];
    const int* ei    = (const int*)d_in[1];
    const int* batch = (const int*)d_in[2];
    const float* W[3], *attS[3], *attD[3], *bias[3], *gamma[3], *beta[3], *mean[3], *var[3];
    for (int l = 0; l < 3; ++l) {
        W[l]     = (const float*)d_in[3 + 8 * l + 0];
        attS[l]  = (const float*)d_in[3 + 8 * l + 1];
        attD[l]  = (const float*)d_in[3 + 8 * l + 2];
        bias[l]  = (const float*)d_in[3 + 8 * l + 3];
        gamma[l] = (const float*)d_in[3 + 8 * l + 4];
        beta[l]  = (const float*)d_in[3 + 8 * l + 5];
        mean[l]  = (const float*)d_in[3 + 8 * l + 6];
        var[l]   = (const float*)d_in[3 + 8 * l + 7];
    }
    const float* fcW = (const float*)d_in[27];
    const float* fcb = (const float*)d_in[28];
    float* out = (float*)d_out;               // [128] pooled sigmoid
    float* alpha_out = (float*)d_out + NG;    // [850000*4] layer-0 alpha

    // Workspace carve-up (256B aligned)
    char* p = (char*)d_ws;
    auto carve = [&](size_t bytes) {
        char* q = p;
        p += (bytes + 255) & ~(size_t)255;
        return q;
    };
    _Float16* Xh    = (_Float16*)carve(sizeof(_Float16) * NN * INDIM);
    _Float16* Wh    = (_Float16*)carve(sizeof(_Float16) * 16384);
    _Float16* Hh    = (_Float16*)carve(sizeof(_Float16) * NN * 64);  // gemm out
    _Float16* Hn    = (_Float16*)carve(sizeof(_Float16) * NN * 64);  // aggr out
    float* AS       = (float*)carve(sizeof(float) * NN * 4);
    float* AD       = (float*)carve(sizeof(float) * NN * 4);
    float* Z        = (float*)carve(sizeof(float) * NN * 4);
    int*   rowstart = (int*)carve(sizeof(int) * NN);
    int*   deg      = (int*)carve(sizeof(int) * NN);
    int*   rank     = (int*)carve(sizeof(int) * ETOT);
    int*   bsums    = (int*)carve(sizeof(int) * 64);
    int*   csr      = (int*)carve(sizeof(int) * ETOT);
    float* psums    = (float*)carve(sizeof(float) * NG * 64);
    int*   pcnt     = (int*)carve(sizeof(int) * NG);

    // fp16 converts + zero-init, one launch
    prep_kernel<<<(PREP_TOT + 255) / 256, 256, 0, stream>>>(
        x, W[0], W[1], W[2], Xh, Wh, deg, psums, pcnt);

    // CSR build
    int nbScan = (NN + 1023) / 1024;
    degree_kernel<<<(ETOT + 255) / 256, 256, 0, stream>>>(ei, deg, rank);
    scan_block_kernel<<<nbScan, 1024, 0, stream>>>(deg, rowstart, bsums);
    scan_sums_kernel<<<1, 64, 0, stream>>>(bsums, nbScan);
    add_offsets_kernel<<<(NN + 255) / 256, 256, 0, stream>>>(rowstart, bsums);
    scatter_kernel<<<(ETOT + 255) / 256, 256, 0, stream>>>(ei, rowstart, rank, csr);

    int edgeBlocks = (NN * 64 + 255) / 256;
    int posBlocks = (ETOT + 255) / 256;
    int gemmBlocks = (NN + 63) / 64;   // 782

    // Layer 0 (K=128), writes Z then alpha
    gemm_att_kernel<128><<<gemmBlocks, 256, 0, stream>>>(Xh, Wh, attS[0], attD[0],
                                                         Hh, AS, AD);
    edge_aggr_kernel<true><<<edgeBlocks, 256, 0, stream>>>(
        Hh, AS, AD, rowstart, deg, csr,
        bias[0], gamma[0], beta[0], mean[0], var[0], Hn, Z);
    alpha_kernel<<<posBlocks, 256, 0, stream>>>(ei, AS, AD, Z, alpha_out);

    // Layer 1 (K=64)
    gemm_att_kernel<64><<<gemmBlocks, 256, 0, stream>>>(Hn, Wh + 8192, attS[1], attD[1],
                                                        Hh, AS, AD);
    edge_aggr_kernel<false><<<edgeBlocks, 256, 0, stream>>>(
        Hh, AS, AD, rowstart, deg, csr,
        bias[1], gamma[1], beta[1], mean[1], var[1], Hn, nullptr);

    // Layer 2 (K=64)
    gemm_att_kernel<64><<<gemmBlocks, 256, 0, stream>>>(Hn, Wh + 12288, attS[2], attD[2],
                                                        Hh, AS, AD);
    edge_aggr_kernel<false><<<edgeBlocks, 256, 0, stream>>>(
        Hh, AS, AD, rowstart, deg, csr,
        bias[2], gamma[2], beta[2], mean[2], var[2], Hn, nullptr);

    // Pool + FC
    int poolWaves = (NN + 63) / 64;
    pool_kernel<<<(poolWaves * 64 + 255) / 256, 256, 0, stream>>>(
        (const __half*)Hn, batch, psums, pcnt);
    fc_kernel<<<(NG * 64 + 255) / 256, 256, 0, stream>>>(psums, pcnt, fcW, fcb, out);
}